// Round 1
// baseline (1445.387 us; speedup 1.0000x reference)
//
#include <hip/hip_runtime.h>
#include <math.h>

#define MDIM 2048
#define PDIM 2198
#define PADB 75
#define NANG 32

// ---------------------------------------------------------------- DCT matrix
// C[k,n] = s_k * cos(pi*(n+0.5)*k/N), s_0 = sqrt(1/N), else sqrt(2/N).
// Reference builds this in float64 then casts -> use double cos on device.
__global__ void gen_dct(float* __restrict__ C) {
    int idx = blockIdx.x * 256 + threadIdx.x;      // 2048*2048 threads
    int k = idx >> 11;
    int n = idx & 2047;
    double arg = 3.14159265358979323846 * (double)(n + 0.5) * (double)k / 2048.0;
    double s = sqrt(((k == 0) ? 1.0 : 2.0) / 2048.0);
    C[idx] = (float)(s * cos(arg));
}

// ---------------------------------------------------------------- SGEMM
// Out[(i+off)*ldOut + (j+off)] = sum_k A[i][k] * (BT ? B[j][k] : B[k][j])
// A, B are 2048x2048 row-major fp32. 64x64 block tile, BK=16, 256 thr, 4x4/thr.
template<int BT>
__global__ __launch_bounds__(256) void sgemm64(const float* __restrict__ A,
                                               const float* __restrict__ B,
                                               float* __restrict__ Out,
                                               int ldOut, int off) {
    __shared__ float As[16][68];   // [k][m], padded row (68*4B % 128B) for banks
    __shared__ float Bs[16][68];   // [k][n]
    const int tid = threadIdx.x;
    const int tx = tid & 15;       // output col group
    const int ty = tid >> 4;       // output row group
    const int row0 = blockIdx.y * 64;
    const int col0 = blockIdx.x * 64;
    const int lr = tid >> 2;       // 0..63 row for A-style loads
    const int lc = tid & 3;        // float4 slot
    const int br = tid >> 4;       // 0..15 row for B row-major load
    const int bc = tid & 15;       // float4 slot

    float acc[4][4] = {};

    for (int k0 = 0; k0 < 2048; k0 += 16) {
        // A tile: A[row0+lr][k0 + lc*4 ..+3] -> As[k][m] (transposed store)
        float4 av = *(const float4*)(A + (size_t)(row0 + lr) * 2048 + k0 + lc * 4);
        As[lc * 4 + 0][lr] = av.x;
        As[lc * 4 + 1][lr] = av.y;
        As[lc * 4 + 2][lr] = av.z;
        As[lc * 4 + 3][lr] = av.w;
        if (BT == 0) {
            // B tile rows k0..k0+15, cols col0..col0+63
            float4 bv = *(const float4*)(B + (size_t)(k0 + br) * 2048 + col0 + bc * 4);
            *(float4*)&Bs[br][bc * 4] = bv;
        } else {
            // Bs[k][n] = B[col0+n][k0+k]
            float4 bv = *(const float4*)(B + (size_t)(col0 + lr) * 2048 + k0 + lc * 4);
            Bs[lc * 4 + 0][lr] = bv.x;
            Bs[lc * 4 + 1][lr] = bv.y;
            Bs[lc * 4 + 2][lr] = bv.z;
            Bs[lc * 4 + 3][lr] = bv.w;
        }
        __syncthreads();
#pragma unroll
        for (int kk = 0; kk < 16; ++kk) {
            float4 a = *(const float4*)&As[kk][ty * 4];
            float4 b = *(const float4*)&Bs[kk][tx * 4];
            const float ar[4] = {a.x, a.y, a.z, a.w};
            const float bregs[4] = {b.x, b.y, b.z, b.w};
#pragma unroll
            for (int i = 0; i < 4; ++i)
#pragma unroll
                for (int j = 0; j < 4; ++j)
                    acc[i][j] = fmaf(ar[i], bregs[j], acc[i][j]);
        }
        __syncthreads();
    }
#pragma unroll
    for (int i = 0; i < 4; ++i)
#pragma unroll
        for (int j = 0; j < 4; ++j)
            Out[(size_t)(row0 + ty * 4 + i + off) * ldOut + (col0 + tx * 4 + j + off)] =
                acc[i][j];
}

// ---------------------------------------------------------------- radon
struct AngleArgs {
    float ca[NANG], sa[NANG], ox[NANG], oy[NANG];
};

__global__ __launch_bounds__(256) void radon_k(const float* __restrict__ padded,
                                               float* __restrict__ lines,
                                               unsigned int* __restrict__ gmax,
                                               AngleArgs args) {
    const int a = blockIdx.y;
    const int c = blockIdx.x * 256 + threadIdx.x;
    float sum = 0.0f;
    if (c < PDIM) {
        const float ca = args.ca[a], sa = args.sa[a];
        const float cf = (float)c;
        const float xbase = fmaf(ca, cf, args.ox[a]);   // + sa*r
        const float ybase = fmaf(-sa, cf, args.oy[a]);  // + ca*r
        for (int r = 0; r < PDIM; ++r) {
            const float rf = (float)r;
            const float x_in = fmaf(sa, rf, xbase);
            const float y_in = fmaf(ca, rf, ybase);
            const float x0 = floorf(x_in);
            const float y0 = floorf(y_in);
            const float wx = x_in - x0;
            const float wy = y_in - y0;
            int xi = (int)x0 % PDIM; if (xi < 0) xi += PDIM;
            int yi = (int)y0 % PDIM; if (yi < 0) yi += PDIM;
            int x1 = xi + 1; if (x1 == PDIM) x1 = 0;
            int y1 = yi + 1; if (y1 == PDIM) y1 = 0;
            const float* r0 = padded + (size_t)yi * PDIM;
            const float* r1 = padded + (size_t)y1 * PDIM;
            const float v00 = r0[xi], v01 = r0[x1];
            const float v10 = r1[xi], v11 = r1[x1];
            const float top = fmaf(wx, v01 - v00, v00);
            const float bot = fmaf(wx, v11 - v10, v10);
            sum = fmaf(wy, bot - top, sum + top);
        }
        lines[(size_t)a * PDIM + c] = sum;
    }
    // global max (monotonic-uint atomicMax)
    float m = (c < PDIM) ? sum : -3.4e38f;
#pragma unroll
    for (int off = 32; off > 0; off >>= 1)
        m = fmaxf(m, __shfl_down(m, off, 64));
    __shared__ float wm[4];
    const int lane = threadIdx.x & 63, wid = threadIdx.x >> 6;
    if (lane == 0) wm[wid] = m;
    __syncthreads();
    if (threadIdx.x == 0) {
        float bm = fmaxf(fmaxf(wm[0], wm[1]), fmaxf(wm[2], wm[3]));
        unsigned int b = __float_as_uint(bm);
        unsigned int key = (b & 0x80000000u) ? ~b : (b | 0x80000000u);
        atomicMax(gmax, key);
    }
}

// ---------------------------------------------------------------- normalize
__global__ void norm_k(const float* __restrict__ lines,
                       const unsigned int* __restrict__ gmax,
                       float* __restrict__ out) {
    int idx = blockIdx.x * 256 + threadIdx.x;
    if (idx >= PDIM * NANG) return;
    unsigned int u = *gmax;
    unsigned int b = (u & 0x80000000u) ? (u & 0x7fffffffu) : ~u;
    float mx = __uint_as_float(b);
    int c = idx >> 5;
    int a = idx & 31;
    out[idx] = lines[(size_t)a * PDIM + c] / mx;
}

// ---------------------------------------------------------------- launch
extern "C" void kernel_launch(void* const* d_in, const int* in_sizes, int n_in,
                              void* d_out, int out_size, void* d_ws, size_t ws_size,
                              hipStream_t stream) {
    (void)in_sizes; (void)n_in; (void)out_size; (void)ws_size;
    const float* img = (const float*)d_in[0];
    float* out = (float*)d_out;

    float* Cm     = (float*)d_ws;                 // 2048*2048
    float* tmp    = Cm + 4194304;                 // 2048*2048
    float* padded = tmp + 4194304;                // 2198*2198
    float* lines  = padded + (size_t)PDIM * PDIM; // 32*2198
    unsigned int* gmax = (unsigned int*)(lines + NANG * PDIM);

    // zero padded image + lines + max accumulator
    hipMemsetAsync(padded, 0,
                   ((size_t)PDIM * PDIM + NANG * PDIM + 1) * sizeof(float), stream);

    gen_dct<<<(2048 * 2048) / 256, 256, 0, stream>>>(Cm);

    dim3 gg(32, 32);
    sgemm64<0><<<gg, 256, 0, stream>>>(Cm, img, tmp, 2048, 0);        // tmp = C*img
    sgemm64<1><<<gg, 256, 0, stream>>>(tmp, Cm, padded, PDIM, PADB);  // d = tmp*C^T

    AngleArgs aa;
    for (int i = 0; i < NANG; ++i) {
        float th = (float)((double)i * 3.14159265358979323846 / 31.0);
        float ca = (float)cos((double)th);
        float sa = (float)sin((double)th);
        aa.ca[i] = ca;
        aa.sa[i] = sa;
        aa.ox[i] = -1099.0f * (ca + sa - 1.0f);
        aa.oy[i] = -1099.0f * (ca - sa - 1.0f);
    }
    radon_k<<<dim3((PDIM + 255) / 256, NANG), 256, 0, stream>>>(padded, lines, gmax, aa);
    norm_k<<<(PDIM * NANG + 255) / 256, 256, 0, stream>>>(lines, gmax, out);
}

// Round 2
// 1270.281 us; speedup vs baseline: 1.1378x; 1.1378x over previous
//
#include <hip/hip_runtime.h>
#include <math.h>

#define MDIM 2048
#define PDIM 2198
#define PADB 75
#define NANG 32
#define RCHUNK 16
#define RROWS 138           // ceil(2198/16)
#define NLINE (NANG * PDIM) // 70336

// ---------------------------------------------------------------- DCT matrix
__global__ void gen_dct(float* __restrict__ C) {
    int idx = blockIdx.x * 256 + threadIdx.x;
    int k = idx >> 11;
    int n = idx & 2047;
    double arg = 3.14159265358979323846 * (double)(n + 0.5) * (double)k / 2048.0;
    double s = sqrt(((k == 0) ? 1.0 : 2.0) / 2048.0);
    C[idx] = (float)(s * cos(arg));
}

// ---------------------------------------------------------------- SGEMM
template<int BT>
__global__ __launch_bounds__(256) void sgemm64(const float* __restrict__ A,
                                               const float* __restrict__ B,
                                               float* __restrict__ Out,
                                               int ldOut, int off) {
    __shared__ float As[16][68];
    __shared__ float Bs[16][68];
    const int tid = threadIdx.x;
    const int tx = tid & 15;
    const int ty = tid >> 4;
    const int row0 = blockIdx.y * 64;
    const int col0 = blockIdx.x * 64;
    const int lr = tid >> 2;
    const int lc = tid & 3;
    const int br = tid >> 4;
    const int bc = tid & 15;

    float acc[4][4] = {};

    for (int k0 = 0; k0 < 2048; k0 += 16) {
        float4 av = *(const float4*)(A + (size_t)(row0 + lr) * 2048 + k0 + lc * 4);
        As[lc * 4 + 0][lr] = av.x;
        As[lc * 4 + 1][lr] = av.y;
        As[lc * 4 + 2][lr] = av.z;
        As[lc * 4 + 3][lr] = av.w;
        if (BT == 0) {
            float4 bv = *(const float4*)(B + (size_t)(k0 + br) * 2048 + col0 + bc * 4);
            *(float4*)&Bs[br][bc * 4] = bv;
        } else {
            float4 bv = *(const float4*)(B + (size_t)(col0 + lr) * 2048 + k0 + lc * 4);
            Bs[lc * 4 + 0][lr] = bv.x;
            Bs[lc * 4 + 1][lr] = bv.y;
            Bs[lc * 4 + 2][lr] = bv.z;
            Bs[lc * 4 + 3][lr] = bv.w;
        }
        __syncthreads();
#pragma unroll
        for (int kk = 0; kk < 16; ++kk) {
            float4 a = *(const float4*)&As[kk][ty * 4];
            float4 b = *(const float4*)&Bs[kk][tx * 4];
            const float ar[4] = {a.x, a.y, a.z, a.w};
            const float bregs[4] = {b.x, b.y, b.z, b.w};
#pragma unroll
            for (int i = 0; i < 4; ++i)
#pragma unroll
                for (int j = 0; j < 4; ++j)
                    acc[i][j] = fmaf(ar[i], bregs[j], acc[i][j]);
        }
        __syncthreads();
    }
#pragma unroll
    for (int i = 0; i < 4; ++i)
#pragma unroll
        for (int j = 0; j < 4; ++j)
            Out[(size_t)(row0 + ty * 4 + i + off) * ldOut + (col0 + tx * 4 + j + off)] =
                acc[i][j];
}

// ---------------------------------------------------------------- transpose
__global__ __launch_bounds__(256) void transpose_k(const float* __restrict__ in,
                                                   float* __restrict__ out) {
    __shared__ float t[32][33];
    const int lx = threadIdx.x & 31;
    const int ly = threadIdx.x >> 5;   // 0..7
    const int bx = blockIdx.x * 32;
    const int by = blockIdx.y * 32;
    const int x = bx + lx;
#pragma unroll
    for (int i = 0; i < 32; i += 8) {
        const int y = by + ly + i;
        if (x < PDIM && y < PDIM) t[ly + i][lx] = in[(size_t)y * PDIM + x];
    }
    __syncthreads();
    const int ox = by + lx;
#pragma unroll
    for (int i = 0; i < 32; i += 8) {
        const int oy = bx + ly + i;
        if (ox < PDIM && oy < PDIM) out[(size_t)oy * PDIM + ox] = t[lx][ly + i];
    }
}

// ---------------------------------------------------------------- radon
struct AngleArgs {
    float ca[NANG], sa[NANG], ox[NANG], oy[NANG];
};

__device__ __forceinline__ float bilin(const float* __restrict__ img,
                                       float x_in, float y_in) {
    const float x0 = floorf(x_in);
    const float y0 = floorf(y_in);
    const float wx = x_in - x0;
    const float wy = y_in - y0;
    int xi = (int)x0 % PDIM; if (xi < 0) xi += PDIM;
    int yi = (int)y0 % PDIM; if (yi < 0) yi += PDIM;
    int x1 = xi + 1; if (x1 == PDIM) x1 = 0;
    int y1 = yi + 1; if (y1 == PDIM) y1 = 0;
    const float* r0 = img + (size_t)yi * PDIM;
    const float* r1 = img + (size_t)y1 * PDIM;
    const float v00 = r0[xi], v01 = r0[x1];
    const float v10 = r1[xi], v11 = r1[x1];
    const float top = fmaf(wx, v01 - v00, v00);
    const float bot = fmaf(wx, v11 - v10, v10);
    return fmaf(wy, bot - top, top);
}

// grid: (ceil(PDIM/256), RCHUNK, NANG)
__global__ __launch_bounds__(256) void radon2(const float* __restrict__ padded,
                                              const float* __restrict__ paddedT,
                                              float* __restrict__ partials,
                                              AngleArgs args) {
    const int a = blockIdx.z;
    const int chunk = blockIdx.y;
    const int c = blockIdx.x * 256 + threadIdx.x;
    if (c >= PDIM) return;
    const int r0 = chunk * RROWS;
    const int r1 = (r0 + RROWS < PDIM) ? r0 + RROWS : PDIM;
    const float ca = args.ca[a], sa = args.sa[a];
    const float cf = (float)c;
    float sum = 0.0f;
    if (fabsf(sa) <= fabsf(ca)) {
        // original image: x = ca*c + sa*r + ox ; y = -sa*c + ca*r + oy
        const float xbase = fmaf(ca, cf, args.ox[a]);
        const float ybase = fmaf(-sa, cf, args.oy[a]);
        for (int r = r0; r < r1; ++r) {
            const float rf = (float)r;
            sum += bilin(padded, fmaf(sa, rf, xbase), fmaf(ca, rf, ybase));
        }
    } else {
        // transposed image: x' = y_in = -sa*c + ca*r + oy ; y' = x_in = ca*c + sa*r + ox
        const float xbase = fmaf(-sa, cf, args.oy[a]);
        const float ybase = fmaf(ca, cf, args.ox[a]);
        for (int r = r0; r < r1; ++r) {
            const float rf = (float)r;
            sum += bilin(paddedT, fmaf(ca, rf, xbase), fmaf(sa, rf, ybase));
        }
    }
    partials[(size_t)chunk * NLINE + a * PDIM + c] = sum;
}

// ---------------------------------------------------------------- reduce+max
__global__ __launch_bounds__(256) void reduce_max_k(const float* __restrict__ partials,
                                                    float* __restrict__ lines,
                                                    unsigned int* __restrict__ gmax) {
    const int idx = blockIdx.x * 256 + threadIdx.x;
    float s = 0.0f;
    const bool valid = idx < NLINE;
    if (valid) {
#pragma unroll
        for (int ch = 0; ch < RCHUNK; ++ch)
            s += partials[(size_t)ch * NLINE + idx];
        lines[idx] = s;
    }
    float m = valid ? s : -3.4e38f;
#pragma unroll
    for (int off = 32; off > 0; off >>= 1)
        m = fmaxf(m, __shfl_down(m, off, 64));
    __shared__ float wm[4];
    const int lane = threadIdx.x & 63, wid = threadIdx.x >> 6;
    if (lane == 0) wm[wid] = m;
    __syncthreads();
    if (threadIdx.x == 0) {
        float bm = fmaxf(fmaxf(wm[0], wm[1]), fmaxf(wm[2], wm[3]));
        unsigned int b = __float_as_uint(bm);
        unsigned int key = (b & 0x80000000u) ? ~b : (b | 0x80000000u);
        atomicMax(gmax, key);
    }
}

// ---------------------------------------------------------------- normalize
__global__ void norm_k(const float* __restrict__ lines,
                       const unsigned int* __restrict__ gmax,
                       float* __restrict__ out) {
    int idx = blockIdx.x * 256 + threadIdx.x;
    if (idx >= NLINE) return;
    unsigned int u = *gmax;
    unsigned int b = (u & 0x80000000u) ? (u & 0x7fffffffu) : ~u;
    float mx = __uint_as_float(b);
    int c = idx >> 5;
    int a = idx & 31;
    out[idx] = lines[(size_t)a * PDIM + c] / mx;
}

// ---------------------------------------------------------------- launch
extern "C" void kernel_launch(void* const* d_in, const int* in_sizes, int n_in,
                              void* d_out, int out_size, void* d_ws, size_t ws_size,
                              hipStream_t stream) {
    (void)in_sizes; (void)n_in; (void)out_size; (void)ws_size;
    const float* img = (const float*)d_in[0];
    float* out = (float*)d_out;

    float* Cm      = (float*)d_ws;                      // 4,194,304
    float* tmp     = Cm + 4194304;                      // 4,194,304
    float* padded  = tmp + 4194304;                     // 4,831,204
    float* paddedT = padded + (size_t)PDIM * PDIM;      // 4,831,204
    float* partials= paddedT + (size_t)PDIM * PDIM;     // 16*70336
    float* lines   = partials + (size_t)RCHUNK * NLINE; // 70336
    unsigned int* gmax = (unsigned int*)(lines + NLINE);

    hipMemsetAsync(padded, 0, (size_t)PDIM * PDIM * sizeof(float), stream);
    hipMemsetAsync(gmax, 0, sizeof(unsigned int), stream);

    gen_dct<<<(2048 * 2048) / 256, 256, 0, stream>>>(Cm);

    dim3 gg(32, 32);
    sgemm64<0><<<gg, 256, 0, stream>>>(Cm, img, tmp, 2048, 0);        // tmp = C*img
    sgemm64<1><<<gg, 256, 0, stream>>>(tmp, Cm, padded, PDIM, PADB);  // d = tmp*C^T

    transpose_k<<<dim3(69, 69), 256, 0, stream>>>(padded, paddedT);

    AngleArgs aa;
    for (int i = 0; i < NANG; ++i) {
        float th = (float)((double)i * 3.14159265358979323846 / 31.0);
        float ca = (float)cos((double)th);
        float sa = (float)sin((double)th);
        aa.ca[i] = ca;
        aa.sa[i] = sa;
        aa.ox[i] = -1099.0f * (ca + sa - 1.0f);
        aa.oy[i] = -1099.0f * (ca - sa - 1.0f);
    }
    radon2<<<dim3(9, RCHUNK, NANG), 256, 0, stream>>>(padded, paddedT, partials, aa);
    reduce_max_k<<<(NLINE + 255) / 256, 256, 0, stream>>>(partials, lines, gmax);
    norm_k<<<(NLINE + 255) / 256, 256, 0, stream>>>(lines, gmax, out);
}

// Round 3
// 1079.532 us; speedup vs baseline: 1.3389x; 1.1767x over previous
//
#include <hip/hip_runtime.h>
#include <math.h>

#define MDIM 2048
#define PDIM 2198
#define PADB 75
#define NANG 32
#define RCH 4               // r-chunks
#define CROWS 550           // ceil(2198/4)
#define NLINE (NANG * PDIM) // 70336

// ---------------------------------------------------------------- DCT matrix
// C[k,n] = s_k * cos(pi*(2n+1)k/4096). t=(2n+1)k <= 8.38M is exact in int/fp32;
// cospif does the pi-multiple range reduction exactly.
__global__ void gen_dct(float* __restrict__ C) {
    int idx = blockIdx.x * 256 + threadIdx.x;
    int k = idx >> 11;
    int n = idx & 2047;
    int t = ((2 * n + 1) * k) & 8191;          // mod 2*4096 (period 2pi)
    float s = sqrtf(((k == 0) ? 1.0f : 2.0f) / 2048.0f);
    C[idx] = s * cospif((float)t * (1.0f / 4096.0f));
}

// ---------------------------------------------------------------- SGEMM
template<int BT>
__global__ __launch_bounds__(256) void sgemm64(const float* __restrict__ A,
                                               const float* __restrict__ B,
                                               float* __restrict__ Out,
                                               int ldOut, int off) {
    __shared__ float As[16][68];
    __shared__ float Bs[16][68];
    const int tid = threadIdx.x;
    const int tx = tid & 15;
    const int ty = tid >> 4;
    const int row0 = blockIdx.y * 64;
    const int col0 = blockIdx.x * 64;
    const int lr = tid >> 2;
    const int lc = tid & 3;
    const int br = tid >> 4;
    const int bc = tid & 15;

    float acc[4][4] = {};

    for (int k0 = 0; k0 < 2048; k0 += 16) {
        float4 av = *(const float4*)(A + (size_t)(row0 + lr) * 2048 + k0 + lc * 4);
        As[lc * 4 + 0][lr] = av.x;
        As[lc * 4 + 1][lr] = av.y;
        As[lc * 4 + 2][lr] = av.z;
        As[lc * 4 + 3][lr] = av.w;
        if (BT == 0) {
            float4 bv = *(const float4*)(B + (size_t)(k0 + br) * 2048 + col0 + bc * 4);
            *(float4*)&Bs[br][bc * 4] = bv;
        } else {
            float4 bv = *(const float4*)(B + (size_t)(col0 + lr) * 2048 + k0 + lc * 4);
            Bs[lc * 4 + 0][lr] = bv.x;
            Bs[lc * 4 + 1][lr] = bv.y;
            Bs[lc * 4 + 2][lr] = bv.z;
            Bs[lc * 4 + 3][lr] = bv.w;
        }
        __syncthreads();
#pragma unroll
        for (int kk = 0; kk < 16; ++kk) {
            float4 a = *(const float4*)&As[kk][ty * 4];
            float4 b = *(const float4*)&Bs[kk][tx * 4];
            const float ar[4] = {a.x, a.y, a.z, a.w};
            const float bregs[4] = {b.x, b.y, b.z, b.w};
#pragma unroll
            for (int i = 0; i < 4; ++i)
#pragma unroll
                for (int j = 0; j < 4; ++j)
                    acc[i][j] = fmaf(ar[i], bregs[j], acc[i][j]);
        }
        __syncthreads();
    }
#pragma unroll
    for (int i = 0; i < 4; ++i)
#pragma unroll
        for (int j = 0; j < 4; ++j)
            Out[(size_t)(row0 + ty * 4 + i + off) * ldOut + (col0 + tx * 4 + j + off)] =
                acc[i][j];
}

// ---------------------------------------------------------------- radon
struct AngleArgs {
    float ca[NANG], sa[NANG], ox[NANG], oy[NANG];
};

// grid: (69 c-blocks, RCH, NANG); block 256 = 4 waves.
// Wave lane layout: lane = c_local*8 + r_local (8x8 (c,r) tile) so the
// wave's sample footprint is ~13x13 pixels for every angle -> ~4x fewer
// cache-line transactions per gather than a 64x1 lane line.
__global__ __launch_bounds__(256) void radon3(const float* __restrict__ padded,
                                              float* __restrict__ partials,
                                              AngleArgs args) {
    const int a = blockIdx.z;
    const int chunk = blockIdx.y;
    const int wid = threadIdx.x >> 6;
    const int lane = threadIdx.x & 63;
    const int c_local = lane >> 3;
    const int r_local = lane & 7;
    const int c = blockIdx.x * 32 + wid * 8 + c_local;

    const int rbase = chunk * CROWS;
    const int rend_c = rbase + CROWS;
    const int rend = (rend_c < PDIM) ? rend_c : PDIM;

    const float ca = args.ca[a], sa = args.sa[a];
    const float cf = (float)c;
    const float xbase = fmaf(ca, cf, args.ox[a]);   // + sa*r
    const float ybase = fmaf(-sa, cf, args.oy[a]);  // + ca*r

    float sum = 0.0f;
    for (int r = rbase + r_local; r < rend; r += 8) {
        const float rf = (float)r;
        const float x_in = fmaf(sa, rf, xbase);
        const float y_in = fmaf(ca, rf, ybase);
        const float x0 = floorf(x_in);
        const float y0 = floorf(y_in);
        const float wx = x_in - x0;
        const float wy = y_in - y0;
        int xi = (int)x0;
        int yi = (int)y0;
        xi += (xi < 0) ? PDIM : 0;  xi -= (xi >= PDIM) ? PDIM : 0;
        yi += (yi < 0) ? PDIM : 0;  yi -= (yi >= PDIM) ? PDIM : 0;
        int x1 = xi + 1; if (x1 == PDIM) x1 = 0;
        int y1 = yi + 1; if (y1 == PDIM) y1 = 0;
        const float* row0 = padded + (size_t)yi * PDIM;
        const float* row1 = padded + (size_t)y1 * PDIM;
        const float v00 = row0[xi], v01 = row0[x1];
        const float v10 = row1[xi], v11 = row1[x1];
        const float top = fmaf(wx, v01 - v00, v00);
        const float bot = fmaf(wx, v11 - v10, v10);
        sum = fmaf(wy, bot - top, sum + top);
    }
    // reduce the 8 r-lanes of each c
    sum += __shfl_xor(sum, 1, 64);
    sum += __shfl_xor(sum, 2, 64);
    sum += __shfl_xor(sum, 4, 64);
    if (r_local == 0 && c < PDIM)
        partials[((size_t)chunk * NANG + a) * PDIM + c] = sum;
}

// ---------------------------------------------------------------- reduce+max
__global__ __launch_bounds__(256) void reduce_max_k(const float* __restrict__ partials,
                                                    float* __restrict__ lines,
                                                    unsigned int* __restrict__ gmax) {
    const int idx = blockIdx.x * 256 + threadIdx.x;
    float s = 0.0f;
    const bool valid = idx < NLINE;
    if (valid) {
#pragma unroll
        for (int ch = 0; ch < RCH; ++ch)
            s += partials[(size_t)ch * NLINE + idx];
        lines[idx] = s;
    }
    float m = valid ? s : -3.4e38f;
#pragma unroll
    for (int off = 32; off > 0; off >>= 1)
        m = fmaxf(m, __shfl_down(m, off, 64));
    __shared__ float wm[4];
    const int lane = threadIdx.x & 63, wid = threadIdx.x >> 6;
    if (lane == 0) wm[wid] = m;
    __syncthreads();
    if (threadIdx.x == 0) {
        float bm = fmaxf(fmaxf(wm[0], wm[1]), fmaxf(wm[2], wm[3]));
        unsigned int b = __float_as_uint(bm);
        unsigned int key = (b & 0x80000000u) ? ~b : (b | 0x80000000u);
        atomicMax(gmax, key);
    }
}

// ---------------------------------------------------------------- normalize
__global__ void norm_k(const float* __restrict__ lines,
                       const unsigned int* __restrict__ gmax,
                       float* __restrict__ out) {
    int idx = blockIdx.x * 256 + threadIdx.x;
    if (idx >= NLINE) return;
    unsigned int u = *gmax;
    unsigned int b = (u & 0x80000000u) ? (u & 0x7fffffffu) : ~u;
    float mx = __uint_as_float(b);
    int c = idx >> 5;
    int a = idx & 31;
    out[idx] = lines[(size_t)a * PDIM + c] / mx;
}

// ---------------------------------------------------------------- launch
extern "C" void kernel_launch(void* const* d_in, const int* in_sizes, int n_in,
                              void* d_out, int out_size, void* d_ws, size_t ws_size,
                              hipStream_t stream) {
    (void)in_sizes; (void)n_in; (void)out_size; (void)ws_size;
    const float* img = (const float*)d_in[0];
    float* out = (float*)d_out;

    float* Cm      = (float*)d_ws;                      // 4,194,304
    float* tmp     = Cm + 4194304;                      // 4,194,304
    float* padded  = tmp + 4194304;                     // 4,831,204
    float* partials= padded + (size_t)PDIM * PDIM;      // RCH*70336
    float* lines   = partials + (size_t)RCH * NLINE;    // 70336
    unsigned int* gmax = (unsigned int*)(lines + NLINE);

    hipMemsetAsync(padded, 0, (size_t)PDIM * PDIM * sizeof(float), stream);
    hipMemsetAsync(gmax, 0, sizeof(unsigned int), stream);

    gen_dct<<<(2048 * 2048) / 256, 256, 0, stream>>>(Cm);

    dim3 gg(32, 32);
    sgemm64<0><<<gg, 256, 0, stream>>>(Cm, img, tmp, 2048, 0);        // tmp = C*img
    sgemm64<1><<<gg, 256, 0, stream>>>(tmp, Cm, padded, PDIM, PADB);  // d = tmp*C^T

    AngleArgs aa;
    for (int i = 0; i < NANG; ++i) {
        float th = (float)((double)i * 3.14159265358979323846 / 31.0);
        float ca = (float)cos((double)th);
        float sa = (float)sin((double)th);
        aa.ca[i] = ca;
        aa.sa[i] = sa;
        aa.ox[i] = -1099.0f * (ca + sa - 1.0f);
        aa.oy[i] = -1099.0f * (ca - sa - 1.0f);
    }
    radon3<<<dim3(69, RCH, NANG), 256, 0, stream>>>(padded, partials, aa);
    reduce_max_k<<<(NLINE + 255) / 256, 256, 0, stream>>>(partials, lines, gmax);
    norm_k<<<(NLINE + 255) / 256, 256, 0, stream>>>(lines, gmax, out);
}

// Round 5
// 687.749 us; speedup vs baseline: 2.1016x; 1.5697x over previous
//
#include <hip/hip_runtime.h>
#include <hip/hip_bf16.h>
#include <math.h>

#define PDIM 2198
#define PADB 75
#define NANG 32
#define RCH 4               // radon r-chunks
#define CROWS 550           // ceil(2198/4)
#define NLINE (NANG * PDIM) // 70336

typedef __attribute__((ext_vector_type(8))) short bf16x8;
typedef __attribute__((ext_vector_type(4))) float f32x4;

#define GLOAD_LDS16(g, l)                                              \
    __builtin_amdgcn_global_load_lds(                                  \
        (const __attribute__((address_space(1))) void*)(g),            \
        (__attribute__((address_space(3))) void*)(l), 16, 0, 0)

// ---------------------------------------------------------------- DCT matrix (bf16)
// C[k,n] = s_k * cos(pi*(2n+1)k/4096); t exact in int, cospif exact pi-reduction.
__global__ void gen_dct(__hip_bfloat16* __restrict__ C) {
    int idx = blockIdx.x * 256 + threadIdx.x;
    int k = idx >> 11;
    int n = idx & 2047;
    int t = ((2 * n + 1) * k) & 8191;
    float s = sqrtf(((k == 0) ? 1.0f : 2.0f) / 2048.0f);
    C[idx] = __float2bfloat16(s * cospif((float)t * (1.0f / 4096.0f)));
}

// ---------------------------------------------------------------- img fp32 -> bf16
__global__ void cvt_img(const float* __restrict__ in, __hip_bfloat16* __restrict__ out) {
    int i = (blockIdx.x * 256 + threadIdx.x) * 4;
    float4 v = *(const float4*)(in + i);
    out[i + 0] = __float2bfloat16(v.x);
    out[i + 1] = __float2bfloat16(v.y);
    out[i + 2] = __float2bfloat16(v.z);
    out[i + 3] = __float2bfloat16(v.w);
}

// ---------------------------------------------------------------- MFMA GEMM (B^T form)
// D[row][col] = sum_k A[row][k] * B[col][k]   (A, B row-major 2048-wide bf16)
// Output is stored TRANSPOSED: out[col][row] (f32 or bf16).
// 128x128 tile, BK=32, 256 thr = 4 waves (2x2), each wave 64x64 = 4x4 16x16x32 frags.
template<int F32OUT>
__global__ __launch_bounds__(256) void gemm_bt(const __hip_bfloat16* __restrict__ A,
                                               const __hip_bfloat16* __restrict__ B,
                                               void* __restrict__ out,
                                               int ldo, int off) {
    __shared__ __hip_bfloat16 Al[128 * 32];
    __shared__ __hip_bfloat16 Bl[128 * 32];
    const int tid = threadIdx.x;
    const int wid = tid >> 6;
    const int lane = tid & 63;
    const int wr = wid >> 1, wc = wid & 1;
    const int l15 = lane & 15, lhi = lane >> 4;
    const int row0 = blockIdx.y * 128;
    const int col0 = blockIdx.x * 128;

    // staging: wave wid covers rows [wid*32, wid*32+32); 2 instrs of 16 rows each.
    const __hip_bfloat16* gA = A + (size_t)(row0 + wid * 32 + (lane >> 2)) * 2048 + (lane & 3) * 8;
    const __hip_bfloat16* gB = B + (size_t)(col0 + wid * 32 + (lane >> 2)) * 2048 + (lane & 3) * 8;
    __hip_bfloat16* lA = Al + wid * 1024;   // 32 rows * 32 elems
    __hip_bfloat16* lB = Bl + wid * 1024;

    f32x4 acc[4][4] = {};

    for (int k0 = 0; k0 < 2048; k0 += 32) {
        GLOAD_LDS16(gA + k0, lA);
        GLOAD_LDS16(gA + 16 * 2048 + k0, lA + 16 * 32);
        GLOAD_LDS16(gB + k0, lB);
        GLOAD_LDS16(gB + 16 * 2048 + k0, lB + 16 * 32);
        __syncthreads();   // compiler drains vmcnt before barrier
        bf16x8 af[4], bfr[4];
#pragma unroll
        for (int m = 0; m < 4; ++m)
            af[m] = *(const bf16x8*)(Al + (wr * 64 + m * 16 + l15) * 32 + lhi * 8);
#pragma unroll
        for (int n = 0; n < 4; ++n)
            bfr[n] = *(const bf16x8*)(Bl + (wc * 64 + n * 16 + l15) * 32 + lhi * 8);
#pragma unroll
        for (int m = 0; m < 4; ++m)
#pragma unroll
            for (int n = 0; n < 4; ++n)
                acc[m][n] = __builtin_amdgcn_mfma_f32_16x16x32_bf16(af[m], bfr[n],
                                                                    acc[m][n], 0, 0, 0);
        __syncthreads();
    }

    // transposed store: D frag mapping row=(lane>>4)*4+q, col=lane&15 (m89-verified).
#pragma unroll
    for (int m = 0; m < 4; ++m) {
        const int row = row0 + wr * 64 + m * 16 + lhi * 4;
#pragma unroll
        for (int n = 0; n < 4; ++n) {
            const int col = col0 + wc * 64 + n * 16 + l15;
            f32x4 v = acc[m][n];
            if (F32OUT) {
                float* p = (float*)out + (size_t)(col + off) * ldo + off + row;
                p[0] = v[0]; p[1] = v[1]; p[2] = v[2]; p[3] = v[3];
            } else {
                __hip_bfloat16* p = (__hip_bfloat16*)out + (size_t)col * 2048 + row;
                p[0] = __float2bfloat16(v[0]);
                p[1] = __float2bfloat16(v[1]);
                p[2] = __float2bfloat16(v[2]);
                p[3] = __float2bfloat16(v[3]);
            }
        }
    }
}

// ---------------------------------------------------------------- radon
struct AngleArgs {
    float ca[NANG], sa[NANG], ox[NANG], oy[NANG];
};

__global__ __launch_bounds__(256) void radon3(const float* __restrict__ padded,
                                              float* __restrict__ partials,
                                              AngleArgs args) {
    const int a = blockIdx.z;
    const int chunk = blockIdx.y;
    const int wid = threadIdx.x >> 6;
    const int lane = threadIdx.x & 63;
    const int c_local = lane >> 3;
    const int r_local = lane & 7;
    const int c = blockIdx.x * 32 + wid * 8 + c_local;

    const int rbase = chunk * CROWS;
    const int rend_c = rbase + CROWS;
    const int rend = (rend_c < PDIM) ? rend_c : PDIM;

    const float ca = args.ca[a], sa = args.sa[a];
    const float cf = (float)c;
    const float xbase = fmaf(ca, cf, args.ox[a]);
    const float ybase = fmaf(-sa, cf, args.oy[a]);

    float sum = 0.0f;
#pragma unroll 4
    for (int r = rbase + r_local; r < rend; r += 8) {
        const float rf = (float)r;
        const float x_in = fmaf(sa, rf, xbase);
        const float y_in = fmaf(ca, rf, ybase);
        const float x0 = floorf(x_in);
        const float y0 = floorf(y_in);
        const float wx = x_in - x0;
        const float wy = y_in - y0;
        int xi = (int)x0;
        int yi = (int)y0;
        xi += (xi < 0) ? PDIM : 0;  xi -= (xi >= PDIM) ? PDIM : 0;
        yi += (yi < 0) ? PDIM : 0;  yi -= (yi >= PDIM) ? PDIM : 0;
        int x1 = xi + 1; if (x1 == PDIM) x1 = 0;
        int y1 = yi + 1; if (y1 == PDIM) y1 = 0;
        const float* row0 = padded + (size_t)yi * PDIM;
        const float* row1 = padded + (size_t)y1 * PDIM;
        const float v00 = row0[xi], v01 = row0[x1];
        const float v10 = row1[xi], v11 = row1[x1];
        const float top = fmaf(wx, v01 - v00, v00);
        const float bot = fmaf(wx, v11 - v10, v10);
        sum = fmaf(wy, bot - top, sum + top);
    }
    sum += __shfl_xor(sum, 1, 64);
    sum += __shfl_xor(sum, 2, 64);
    sum += __shfl_xor(sum, 4, 64);
    if (r_local == 0 && c < PDIM)
        partials[((size_t)chunk * NANG + a) * PDIM + c] = sum;
}

// ---------------------------------------------------------------- reduce+max
__global__ __launch_bounds__(256) void reduce_max_k(const float* __restrict__ partials,
                                                    float* __restrict__ lines,
                                                    unsigned int* __restrict__ gmax) {
    const int idx = blockIdx.x * 256 + threadIdx.x;
    float s = 0.0f;
    const bool valid = idx < NLINE;
    if (valid) {
#pragma unroll
        for (int ch = 0; ch < RCH; ++ch)
            s += partials[(size_t)ch * NLINE + idx];
        lines[idx] = s;
    }
    float m = valid ? s : -3.4e38f;
#pragma unroll
    for (int off = 32; off > 0; off >>= 1)
        m = fmaxf(m, __shfl_down(m, off, 64));
    __shared__ float wm[4];
    const int lane = threadIdx.x & 63, wid = threadIdx.x >> 6;
    if (lane == 0) wm[wid] = m;
    __syncthreads();
    if (threadIdx.x == 0) {
        float bm = fmaxf(fmaxf(wm[0], wm[1]), fmaxf(wm[2], wm[3]));
        unsigned int b = __float_as_uint(bm);
        unsigned int key = (b & 0x80000000u) ? ~b : (b | 0x80000000u);
        atomicMax(gmax, key);
    }
}

// ---------------------------------------------------------------- normalize
__global__ void norm_k(const float* __restrict__ lines,
                       const unsigned int* __restrict__ gmax,
                       float* __restrict__ out) {
    int idx = blockIdx.x * 256 + threadIdx.x;
    if (idx >= NLINE) return;
    unsigned int u = *gmax;
    unsigned int b = (u & 0x80000000u) ? (u & 0x7fffffffu) : ~u;
    float mx = __uint_as_float(b);
    int c = idx >> 5;
    int a = idx & 31;
    out[idx] = lines[(size_t)a * PDIM + c] / mx;
}

// ---------------------------------------------------------------- launch
extern "C" void kernel_launch(void* const* d_in, const int* in_sizes, int n_in,
                              void* d_out, int out_size, void* d_ws, size_t ws_size,
                              hipStream_t stream) {
    (void)in_sizes; (void)n_in; (void)out_size; (void)ws_size;
    const float* img = (const float*)d_in[0];
    float* out = (float*)d_out;

    __hip_bfloat16* Cbf   = (__hip_bfloat16*)d_ws;      // 8 MB
    __hip_bfloat16* imgbf = Cbf + 4194304;              // 8 MB
    __hip_bfloat16* uT    = imgbf + 4194304;            // 8 MB
    float* padded  = (float*)(uT + 4194304);            // 19.3 MB
    float* partials= padded + (size_t)PDIM * PDIM;      // RCH*NLINE
    float* lines   = partials + (size_t)RCH * NLINE;
    unsigned int* gmax = (unsigned int*)(lines + NLINE);

    hipMemsetAsync(padded, 0, (size_t)PDIM * PDIM * sizeof(float), stream);
    hipMemsetAsync(gmax, 0, sizeof(unsigned int), stream);

    gen_dct<<<16384, 256, 0, stream>>>(Cbf);
    cvt_img<<<4096, 256, 0, stream>>>(img, imgbf);

    dim3 gg(16, 16);
    // u = img*C^T, stored transposed (uT = C*img^T), bf16
    gemm_bt<0><<<gg, 256, 0, stream>>>(imgbf, Cbf, uT, 2048, 0);
    // e = uT*C^T = d^T, stored transposed into padded => padded = d, f32
    gemm_bt<1><<<gg, 256, 0, stream>>>(uT, Cbf, padded, PDIM, PADB);

    AngleArgs aa;
    for (int i = 0; i < NANG; ++i) {
        float th = (float)((double)i * 3.14159265358979323846 / 31.0);
        float ca = (float)cos((double)th);
        float sa = (float)sin((double)th);
        aa.ca[i] = ca;
        aa.sa[i] = sa;
        aa.ox[i] = -1099.0f * (ca + sa - 1.0f);
        aa.oy[i] = -1099.0f * (ca - sa - 1.0f);
    }
    radon3<<<dim3(69, RCH, NANG), 256, 0, stream>>>(padded, partials, aa);
    reduce_max_k<<<(NLINE + 255) / 256, 256, 0, stream>>>(partials, lines, gmax);
    norm_k<<<(NLINE + 255) / 256, 256, 0, stream>>>(lines, gmax, out);
}

// Round 6
// 426.925 us; speedup vs baseline: 3.3856x; 1.6109x over previous
//
#include <hip/hip_runtime.h>
#include <hip/hip_bf16.h>
#include <math.h>

#define PDIM 2198
#define PADB 75
#define NANG 32
#define NLINE (NANG * PDIM) // 70336

// radon4 geometry
#define CB 32      // c-values per block
#define RW 32      // r-values per window
#define NWIN 69    // ceil(2198/32)
#define TS 48      // staged box rows/cols (span proof: <=46 used)
#define TSTRIDE 49 // odd stride -> conflict-free at axis angles

typedef __attribute__((ext_vector_type(8))) short bf16x8;
typedef __attribute__((ext_vector_type(4))) float f32x4;

#define GLOAD_LDS16(g, l)                                              \
    __builtin_amdgcn_global_load_lds(                                  \
        (const __attribute__((address_space(1))) void*)(g),            \
        (__attribute__((address_space(3))) void*)(l), 16, 0, 0)
#define GLOAD_LDS4(g, l)                                               \
    __builtin_amdgcn_global_load_lds(                                  \
        (const __attribute__((address_space(1))) void*)(g),            \
        (__attribute__((address_space(3))) void*)(l), 4, 0, 0)

// ---------------------------------------------------------------- DCT matrix (bf16)
__global__ void gen_dct(__hip_bfloat16* __restrict__ C) {
    int idx = blockIdx.x * 256 + threadIdx.x;
    int k = idx >> 11;
    int n = idx & 2047;
    int t = ((2 * n + 1) * k) & 8191;
    float s = sqrtf(((k == 0) ? 1.0f : 2.0f) / 2048.0f);
    C[idx] = __float2bfloat16(s * cospif((float)t * (1.0f / 4096.0f)));
}

// ---------------------------------------------------------------- img fp32 -> bf16
__global__ void cvt_img(const float* __restrict__ in, __hip_bfloat16* __restrict__ out) {
    int i = (blockIdx.x * 256 + threadIdx.x) * 4;
    float4 v = *(const float4*)(in + i);
    out[i + 0] = __float2bfloat16(v.x);
    out[i + 1] = __float2bfloat16(v.y);
    out[i + 2] = __float2bfloat16(v.z);
    out[i + 3] = __float2bfloat16(v.w);
}

// ---------------------------------------------------------------- MFMA GEMM (B^T form)
// D[row][col] = sum_k A[row][k]*B[col][k]; output stored TRANSPOSED out[col][row].
template<int F32OUT>
__global__ __launch_bounds__(256) void gemm_bt(const __hip_bfloat16* __restrict__ A,
                                               const __hip_bfloat16* __restrict__ B,
                                               void* __restrict__ out,
                                               int ldo, int off) {
    __shared__ __hip_bfloat16 Al[128 * 32];
    __shared__ __hip_bfloat16 Bl[128 * 32];
    const int tid = threadIdx.x;
    const int wid = tid >> 6;
    const int lane = tid & 63;
    const int wr = wid >> 1, wc = wid & 1;
    const int l15 = lane & 15, lhi = lane >> 4;
    const int row0 = blockIdx.y * 128;
    const int col0 = blockIdx.x * 128;

    const __hip_bfloat16* gA = A + (size_t)(row0 + wid * 32 + (lane >> 2)) * 2048 + (lane & 3) * 8;
    const __hip_bfloat16* gB = B + (size_t)(col0 + wid * 32 + (lane >> 2)) * 2048 + (lane & 3) * 8;
    __hip_bfloat16* lA = Al + wid * 1024;
    __hip_bfloat16* lB = Bl + wid * 1024;

    f32x4 acc[4][4] = {};

    for (int k0 = 0; k0 < 2048; k0 += 32) {
        GLOAD_LDS16(gA + k0, lA);
        GLOAD_LDS16(gA + 16 * 2048 + k0, lA + 16 * 32);
        GLOAD_LDS16(gB + k0, lB);
        GLOAD_LDS16(gB + 16 * 2048 + k0, lB + 16 * 32);
        __syncthreads();
        bf16x8 af[4], bfr[4];
#pragma unroll
        for (int m = 0; m < 4; ++m)
            af[m] = *(const bf16x8*)(Al + (wr * 64 + m * 16 + l15) * 32 + lhi * 8);
#pragma unroll
        for (int n = 0; n < 4; ++n)
            bfr[n] = *(const bf16x8*)(Bl + (wc * 64 + n * 16 + l15) * 32 + lhi * 8);
#pragma unroll
        for (int m = 0; m < 4; ++m)
#pragma unroll
            for (int n = 0; n < 4; ++n)
                acc[m][n] = __builtin_amdgcn_mfma_f32_16x16x32_bf16(af[m], bfr[n],
                                                                    acc[m][n], 0, 0, 0);
        __syncthreads();
    }

#pragma unroll
    for (int m = 0; m < 4; ++m) {
        const int row = row0 + wr * 64 + m * 16 + lhi * 4;
#pragma unroll
        for (int n = 0; n < 4; ++n) {
            const int col = col0 + wc * 64 + n * 16 + l15;
            f32x4 v = acc[m][n];
            if (F32OUT) {
                float* p = (float*)out + (size_t)(col + off) * ldo + off + row;
                p[0] = v[0]; p[1] = v[1]; p[2] = v[2]; p[3] = v[3];
            } else {
                __hip_bfloat16* p = (__hip_bfloat16*)out + (size_t)col * 2048 + row;
                p[0] = __float2bfloat16(v[0]);
                p[1] = __float2bfloat16(v[1]);
                p[2] = __float2bfloat16(v[2]);
                p[3] = __float2bfloat16(v[3]);
            }
        }
    }
}

// ---------------------------------------------------------------- radon (LDS band-staged)
struct AngleArgs {
    float ca[NANG], sa[NANG], ox[NANG], oy[NANG];
};

// grid: (69 c-blocks, 32 angles), 256 threads = 4 waves.
// Per r-window of 32: stage the 48x48 sample bounding box into LDS (wrap at
// staging via per-lane wrapped global addr + linear LDS dest), then 32x32
// samples read 4x b32 from LDS with NO mod. Double-buffered, 1 barrier/window.
__global__ __launch_bounds__(256) void radon4(const float* __restrict__ padded,
                                              float* __restrict__ lines,
                                              AngleArgs args) {
    __shared__ float tile[2][TS * TSTRIDE];
    __shared__ float red[4][CB];
    const int a = blockIdx.y;
    const int c0 = blockIdx.x * CB;
    const int t = threadIdx.x;
    const int wid = t >> 6, lane = t & 63;
    const int cl = t & 31;       // c lane
    const int rgrp = t >> 5;     // 0..7
    const float ca = args.ca[a], sa = args.sa[a];
    const float ox = args.ox[a], oy = args.oy[a];

    const float cf = (float)(c0 + cl);
    const float xbase = fmaf(ca, cf, ox);    // + sa*r
    const float ybase = fmaf(-sa, cf, oy);   // + ca*r

    // corner bases (bit-identical ops to per-lane bases -> exact bounds by
    // monotonicity of correctly-rounded fmaf)
    const float xbA = fmaf(ca, (float)c0, ox);
    const float xbB = fmaf(ca, (float)(c0 + CB - 1), ox);
    const float ybA = fmaf(-sa, (float)c0, oy);
    const float ybB = fmaf(-sa, (float)(c0 + CB - 1), oy);

    float sum = 0.0f;

    // ---- box origin for window w (recomputed identically in stage & compute)
    auto origin = [&](int w, int& bx0, int& by0) {
        const float rf0 = (float)(w * RW);
        const float rf1 = (float)(w * RW + RW - 1);
        float minx = fminf(fminf(fmaf(sa, rf0, xbA), fmaf(sa, rf1, xbA)),
                           fminf(fmaf(sa, rf0, xbB), fmaf(sa, rf1, xbB)));
        float miny = fminf(fminf(fmaf(ca, rf0, ybA), fmaf(ca, rf1, ybA)),
                           fminf(fmaf(ca, rf0, ybB), fmaf(ca, rf1, ybB)));
        bx0 = (int)floorf(minx) - 1;   // -1 guard
        by0 = (int)floorf(miny) - 1;
    };

    auto stage = [&](int w, int buf) {
        int bx0, by0;
        origin(w, bx0, by0);
        if (lane < TS) {
            int gx = bx0 + lane;
            gx += (gx < 0) ? PDIM : 0;  gx -= (gx >= PDIM) ? PDIM : 0;
#pragma unroll
            for (int j = 0; j < TS / 4; ++j) {
                const int yy = wid * (TS / 4) + j;    // wave-uniform row
                int gy = by0 + yy;
                gy += (gy < 0) ? PDIM : 0;  gy -= (gy >= PDIM) ? PDIM : 0;
                GLOAD_LDS4(padded + (size_t)gy * PDIM + gx,
                           &tile[buf][yy * TSTRIDE]);
            }
        }
    };

    auto compute = [&](int w, int buf) {
        int bx0, by0;
        origin(w, bx0, by0);
        const float bx0f = (float)bx0, by0f = (float)by0;
        const float* tb = &tile[buf][0];
        const int r0 = w * RW;
#pragma unroll
        for (int k = 0; k < 4; ++k) {
            const int r = r0 + rgrp + 8 * k;
            const float rf = (float)r;
            const float x_in = fmaf(sa, rf, xbase);
            const float y_in = fmaf(ca, rf, ybase);
            const float xl = x_in - bx0f;          // exact (18-bit result)
            const float yl = y_in - by0f;
            const float x0f = floorf(xl), y0f = floorf(yl);
            const float wx = xl - x0f, wy = yl - y0f;
            const int xi = (int)x0f, yi = (int)y0f;
            const float* p = tb + yi * TSTRIDE + xi;
            const float v00 = p[0], v01 = p[1];
            const float v10 = p[TSTRIDE], v11 = p[TSTRIDE + 1];
            const float top = fmaf(wx, v01 - v00, v00);
            const float bot = fmaf(wx, v11 - v10, v10);
            if (r < PDIM) sum = fmaf(wy, bot - top, sum + top);
        }
    };

    stage(0, 0);
    __syncthreads();                       // drain stage(0)
    for (int w = 0; w < NWIN; ++w) {
        if (w + 1 < NWIN) stage(w + 1, (w + 1) & 1);  // overlaps compute(w)
        compute(w, w & 1);
        __syncthreads();                   // drains stage(w+1); frees buf for w+2
    }

    // reduce 8 rgrp per c: lanes l and l^32 share c
    sum += __shfl_xor(sum, 32, 64);
    if (lane < 32) red[wid][cl] = sum;
    __syncthreads();
    if (t < 32) {
        const int c = c0 + t;
        if (c < PDIM)
            lines[a * PDIM + c] = red[0][t] + red[1][t] + red[2][t] + red[3][t];
    }
}

// ---------------------------------------------------------------- max
__global__ __launch_bounds__(256) void max_k(const float* __restrict__ lines,
                                             unsigned int* __restrict__ gmax) {
    const int idx = blockIdx.x * 256 + threadIdx.x;
    float m = (idx < NLINE) ? lines[idx] : -3.4e38f;
#pragma unroll
    for (int off = 32; off > 0; off >>= 1)
        m = fmaxf(m, __shfl_down(m, off, 64));
    __shared__ float wm[4];
    const int lane = threadIdx.x & 63, wid = threadIdx.x >> 6;
    if (lane == 0) wm[wid] = m;
    __syncthreads();
    if (threadIdx.x == 0) {
        float bm = fmaxf(fmaxf(wm[0], wm[1]), fmaxf(wm[2], wm[3]));
        unsigned int b = __float_as_uint(bm);
        unsigned int key = (b & 0x80000000u) ? ~b : (b | 0x80000000u);
        atomicMax(gmax, key);
    }
}

// ---------------------------------------------------------------- normalize
__global__ void norm_k(const float* __restrict__ lines,
                       const unsigned int* __restrict__ gmax,
                       float* __restrict__ out) {
    int idx = blockIdx.x * 256 + threadIdx.x;
    if (idx >= NLINE) return;
    unsigned int u = *gmax;
    unsigned int b = (u & 0x80000000u) ? (u & 0x7fffffffu) : ~u;
    float mx = __uint_as_float(b);
    int c = idx >> 5;
    int a = idx & 31;
    out[idx] = lines[(size_t)a * PDIM + c] / mx;
}

// ---------------------------------------------------------------- launch
extern "C" void kernel_launch(void* const* d_in, const int* in_sizes, int n_in,
                              void* d_out, int out_size, void* d_ws, size_t ws_size,
                              hipStream_t stream) {
    (void)in_sizes; (void)n_in; (void)out_size; (void)ws_size;
    const float* img = (const float*)d_in[0];
    float* out = (float*)d_out;

    __hip_bfloat16* Cbf   = (__hip_bfloat16*)d_ws;      // 8 MB
    __hip_bfloat16* imgbf = Cbf + 4194304;              // 8 MB
    __hip_bfloat16* uT    = imgbf + 4194304;            // 8 MB
    float* padded  = (float*)(uT + 4194304);            // 19.3 MB
    float* lines   = padded + (size_t)PDIM * PDIM;
    unsigned int* gmax = (unsigned int*)(lines + NLINE);

    hipMemsetAsync(padded, 0, (size_t)PDIM * PDIM * sizeof(float), stream);
    hipMemsetAsync(gmax, 0, sizeof(unsigned int), stream);

    gen_dct<<<16384, 256, 0, stream>>>(Cbf);
    cvt_img<<<4096, 256, 0, stream>>>(img, imgbf);

    dim3 gg(16, 16);
    gemm_bt<0><<<gg, 256, 0, stream>>>(imgbf, Cbf, uT, 2048, 0);      // uT = (img*C^T)^T
    gemm_bt<1><<<gg, 256, 0, stream>>>(uT, Cbf, padded, PDIM, PADB);  // padded = d

    AngleArgs aa;
    for (int i = 0; i < NANG; ++i) {
        float th = (float)((double)i * 3.14159265358979323846 / 31.0);
        float ca = (float)cos((double)th);
        float sa = (float)sin((double)th);
        aa.ca[i] = ca;
        aa.sa[i] = sa;
        aa.ox[i] = -1099.0f * (ca + sa - 1.0f);
        aa.oy[i] = -1099.0f * (ca - sa - 1.0f);
    }
    radon4<<<dim3(NWIN, NANG), 256, 0, stream>>>(padded, lines, aa);
    max_k<<<(NLINE + 255) / 256, 256, 0, stream>>>(lines, gmax);
    norm_k<<<(NLINE + 255) / 256, 256, 0, stream>>>(lines, gmax, out);
}

// Round 7
// 352.784 us; speedup vs baseline: 4.0971x; 1.2102x over previous
//
#include <hip/hip_runtime.h>
#include <hip/hip_bf16.h>
#include <math.h>

#define PDIM 2198
#define PADB 75
#define NANG 32
#define NLINE (NANG * PDIM) // 70336

// radon5 geometry
#define CB 32      // c-values per block
#define RW 32      // r-values per window
#define NWIN 69    // ceil(2198/32)
#define TS 48      // staged box rows (span proof: <=47 used)
#define TSTRIDE 52 // staged cols per row; multiple of 4 for 16B staging

typedef __attribute__((ext_vector_type(8))) short bf16x8;
typedef __attribute__((ext_vector_type(4))) float f32x4;

#define GLOAD_LDS16(g, l)                                              \
    __builtin_amdgcn_global_load_lds(                                  \
        (const __attribute__((address_space(1))) void*)(g),            \
        (__attribute__((address_space(3))) void*)(l), 16, 0, 0)
#define GLOAD_LDS4(g, l)                                               \
    __builtin_amdgcn_global_load_lds(                                  \
        (const __attribute__((address_space(1))) void*)(g),            \
        (__attribute__((address_space(3))) void*)(l), 4, 0, 0)

#if __has_builtin(__builtin_amdgcn_fractf)
#define FRACTF(x) __builtin_amdgcn_fractf(x)
#else
#define FRACTF(x) ((x) - floorf(x))
#endif

// ---------------------------------------------------------------- DCT matrix (bf16)
__global__ void gen_dct(__hip_bfloat16* __restrict__ C) {
    int idx = blockIdx.x * 256 + threadIdx.x;
    int k = idx >> 11;
    int n = idx & 2047;
    int t = ((2 * n + 1) * k) & 8191;
    float s = sqrtf(((k == 0) ? 1.0f : 2.0f) / 2048.0f);
    C[idx] = __float2bfloat16(s * cospif((float)t * (1.0f / 4096.0f)));
}

// ---------------------------------------------------------------- img fp32 -> bf16
__global__ void cvt_img(const float* __restrict__ in, __hip_bfloat16* __restrict__ out) {
    int i = (blockIdx.x * 256 + threadIdx.x) * 4;
    float4 v = *(const float4*)(in + i);
    out[i + 0] = __float2bfloat16(v.x);
    out[i + 1] = __float2bfloat16(v.y);
    out[i + 2] = __float2bfloat16(v.z);
    out[i + 3] = __float2bfloat16(v.w);
}

// ---------------------------------------------------------------- MFMA GEMM (B^T form)
// D[row][col] = sum_k A[row][k]*B[col][k]; output stored TRANSPOSED out[col][row].
template<int F32OUT>
__global__ __launch_bounds__(256) void gemm_bt(const __hip_bfloat16* __restrict__ A,
                                               const __hip_bfloat16* __restrict__ B,
                                               void* __restrict__ out,
                                               int ldo, int off) {
    __shared__ __hip_bfloat16 Al[128 * 32];
    __shared__ __hip_bfloat16 Bl[128 * 32];
    const int tid = threadIdx.x;
    const int wid = tid >> 6;
    const int lane = tid & 63;
    const int wr = wid >> 1, wc = wid & 1;
    const int l15 = lane & 15, lhi = lane >> 4;
    const int row0 = blockIdx.y * 128;
    const int col0 = blockIdx.x * 128;

    const __hip_bfloat16* gA = A + (size_t)(row0 + wid * 32 + (lane >> 2)) * 2048 + (lane & 3) * 8;
    const __hip_bfloat16* gB = B + (size_t)(col0 + wid * 32 + (lane >> 2)) * 2048 + (lane & 3) * 8;
    __hip_bfloat16* lA = Al + wid * 1024;
    __hip_bfloat16* lB = Bl + wid * 1024;

    f32x4 acc[4][4] = {};

    for (int k0 = 0; k0 < 2048; k0 += 32) {
        GLOAD_LDS16(gA + k0, lA);
        GLOAD_LDS16(gA + 16 * 2048 + k0, lA + 16 * 32);
        GLOAD_LDS16(gB + k0, lB);
        GLOAD_LDS16(gB + 16 * 2048 + k0, lB + 16 * 32);
        __syncthreads();
        bf16x8 af[4], bfr[4];
#pragma unroll
        for (int m = 0; m < 4; ++m)
            af[m] = *(const bf16x8*)(Al + (wr * 64 + m * 16 + l15) * 32 + lhi * 8);
#pragma unroll
        for (int n = 0; n < 4; ++n)
            bfr[n] = *(const bf16x8*)(Bl + (wc * 64 + n * 16 + l15) * 32 + lhi * 8);
#pragma unroll
        for (int m = 0; m < 4; ++m)
#pragma unroll
            for (int n = 0; n < 4; ++n)
                acc[m][n] = __builtin_amdgcn_mfma_f32_16x16x32_bf16(af[m], bfr[n],
                                                                    acc[m][n], 0, 0, 0);
        __syncthreads();
    }

#pragma unroll
    for (int m = 0; m < 4; ++m) {
        const int row = row0 + wr * 64 + m * 16 + lhi * 4;
#pragma unroll
        for (int n = 0; n < 4; ++n) {
            const int col = col0 + wc * 64 + n * 16 + l15;
            f32x4 v = acc[m][n];
            if (F32OUT) {
                float* p = (float*)out + (size_t)(col + off) * ldo + off + row;
                p[0] = v[0]; p[1] = v[1]; p[2] = v[2]; p[3] = v[3];
            } else {
                __hip_bfloat16* p = (__hip_bfloat16*)out + (size_t)col * 2048 + row;
                p[0] = __float2bfloat16(v[0]);
                p[1] = __float2bfloat16(v[1]);
                p[2] = __float2bfloat16(v[2]);
                p[3] = __float2bfloat16(v[3]);
            }
        }
    }
}

// ---------------------------------------------------------------- radon (LDS band-staged)
struct AngleArgs {
    float ca[NANG], sa[NANG], ox[NANG], oy[NANG];
};

// grid: (69 c-blocks, 32 angles), 256 threads = 4 waves.
// 8x8 (c,r) lane tile per wave: wave wid covers c = c0+wid*8+(lane>>3),
// r = r0+(lane&7)+8k. LDS lane strides mix +-ca and +-sa directions ->
// worst-case bank aliasing ~8-way instead of 32-way (the radon4 regression).
__global__ __launch_bounds__(256) void radon5(const float* __restrict__ padded,
                                              float* __restrict__ lines,
                                              AngleArgs args) {
    __shared__ float tile[2][TS * TSTRIDE];
    __shared__ float red[4][8];
    const int a = blockIdx.y;
    const int c0 = blockIdx.x * CB;
    const int t = threadIdx.x;
    const int wid = t >> 6, lane = t & 63;
    const int cl = lane >> 3;   // 0..7 c within wave
    const int rl = lane & 7;    // 0..7 r group
    const int c = c0 + wid * 8 + cl;
    const float ca = args.ca[a], sa = args.sa[a];   // sa >= 0 for theta in [0,pi]
    const float ox = args.ox[a], oy = args.oy[a];

    const float cf = (float)c;
    const float xbase = fmaf(ca, cf, ox);    // + sa*r
    const float ybase = fmaf(-sa, cf, oy);   // + ca*r

    // corner bases; bit-identical op sequence to xbase/ybase -> exact bounds
    // via monotonicity of correctly-rounded fmaf.
    const float xbMin = fminf(fmaf(ca, (float)c0, ox), fmaf(ca, (float)(c0 + CB - 1), ox));
    const float ybMin = fminf(fmaf(-sa, (float)c0, oy), fmaf(-sa, (float)(c0 + CB - 1), oy));
    const bool caPos = (ca >= 0.0f);

    float sum = 0.0f;

    // box origin for window w: sa>=0 -> min x at r=r0; min y at r0 (ca>=0) else r0+RW-1
    auto origin = [&](int w, int& bx0, int& by0) {
        const float rx = (float)(w * RW);
        const float ry = caPos ? rx : (float)(w * RW + RW - 1);
        bx0 = (int)floorf(fmaf(sa, rx, xbMin)) - 1;
        by0 = (int)floorf(fmaf(ca, ry, ybMin)) - 1;
    };

    auto stage = [&](int buf, int bx0, int by0) {
        int bxs = bx0;                       // bx0 in [-78, 2257]
        bxs += (bxs < 0) ? PDIM : 0;
        bxs -= (bxs >= PDIM) ? PDIM : 0;
        if (bxs + TSTRIDE - 1 < PDIM) {
            // fast path: x-range wrap-free after uniform shift; 16B DMA.
            const int slab = wid * 12;       // 12 rows of 52 dwords per wave
#pragma unroll
            for (int iss = 0; iss < 3; ++iss) {
                const int d = iss * 256 + lane * 4;    // dword in slab, mult of 4
                if (d < 12 * TSTRIDE) {
                    const int rr = d / TSTRIDE;
                    const int col = d - rr * TSTRIDE;  // multiple of 4 (52%4==0)
                    int gy = by0 + slab + rr;
                    gy += (gy < 0) ? PDIM : 0;
                    gy -= (gy >= PDIM) ? PDIM : 0;
                    GLOAD_LDS16(padded + (size_t)gy * PDIM + bxs + col,
                                &tile[buf][slab * TSTRIDE + iss * 256]);
                }
            }
        } else {
            // rare (~5% of windows): x-range crosses the wrap seam; 4B per dword.
            if (lane < TSTRIDE) {
                int gx = bx0 + lane;
                gx += (gx < 0) ? PDIM : 0;
                gx -= (gx >= PDIM) ? PDIM : 0;
#pragma unroll
                for (int j = 0; j < 12; ++j) {
                    const int row = wid * 12 + j;
                    int gy = by0 + row;
                    gy += (gy < 0) ? PDIM : 0;
                    gy -= (gy >= PDIM) ? PDIM : 0;
                    GLOAD_LDS4(padded + (size_t)gy * PDIM + gx,
                               &tile[buf][row * TSTRIDE]);
                }
            }
        }
    };

    auto compute = [&](int r0, int buf, int bx0, int by0, bool last) {
        const float bx0f = (float)bx0, by0f = (float)by0;
        const float* tb = &tile[buf][0];
#pragma unroll
        for (int k = 0; k < 4; ++k) {
            const int r = r0 + rl + 8 * k;
            const float rf = (float)r;
            const float x_in = fmaf(sa, rf, xbase);
            const float y_in = fmaf(ca, rf, ybase);
            const float xl = x_in - bx0f;          // exact; >= 1
            const float yl = y_in - by0f;
            const int xi = (int)xl;
            const int yi = (int)yl;
            const float wx = FRACTF(xl);
            const float wy = FRACTF(yl);
            const float* p = tb + yi * TSTRIDE + xi;
            const float v00 = p[0], v01 = p[1];
            const float v10 = p[TSTRIDE], v11 = p[TSTRIDE + 1];
            const float top = fmaf(wx, v01 - v00, v00);
            const float bot = fmaf(wx, v11 - v10, v10);
            if (!last || r < PDIM) sum = fmaf(wy, bot - top, sum + top);
        }
    };

    int bxc, byc, bxn, byn;
    origin(0, bxc, byc);
    stage(0, bxc, byc);
    __syncthreads();
    for (int w = 0; w < NWIN - 1; ++w) {
        origin(w + 1, bxn, byn);
        stage((w + 1) & 1, bxn, byn);          // overlaps compute(w)
        compute(w * RW, w & 1, bxc, byc, false);
        __syncthreads();                        // drains stage(w+1)
        bxc = bxn; byc = byn;
    }
    compute((NWIN - 1) * RW, (NWIN - 1) & 1, bxc, byc, true);

    // reduce the 8 r-lanes of each c
    sum += __shfl_xor(sum, 1, 64);
    sum += __shfl_xor(sum, 2, 64);
    sum += __shfl_xor(sum, 4, 64);
    if (rl == 0) red[wid][cl] = sum;
    __syncthreads();
    if (t < 32 && c0 + t < PDIM)
        lines[a * PDIM + c0 + t] = red[t >> 3][t & 7];
}

// ---------------------------------------------------------------- max
__global__ __launch_bounds__(256) void max_k(const float* __restrict__ lines,
                                             unsigned int* __restrict__ gmax) {
    const int idx = blockIdx.x * 256 + threadIdx.x;
    float m = (idx < NLINE) ? lines[idx] : -3.4e38f;
#pragma unroll
    for (int off = 32; off > 0; off >>= 1)
        m = fmaxf(m, __shfl_down(m, off, 64));
    __shared__ float wm[4];
    const int lane = threadIdx.x & 63, wid = threadIdx.x >> 6;
    if (lane == 0) wm[wid] = m;
    __syncthreads();
    if (threadIdx.x == 0) {
        float bm = fmaxf(fmaxf(wm[0], wm[1]), fmaxf(wm[2], wm[3]));
        unsigned int b = __float_as_uint(bm);
        unsigned int key = (b & 0x80000000u) ? ~b : (b | 0x80000000u);
        atomicMax(gmax, key);
    }
}

// ---------------------------------------------------------------- normalize
__global__ void norm_k(const float* __restrict__ lines,
                       const unsigned int* __restrict__ gmax,
                       float* __restrict__ out) {
    int idx = blockIdx.x * 256 + threadIdx.x;
    if (idx >= NLINE) return;
    unsigned int u = *gmax;
    unsigned int b = (u & 0x80000000u) ? (u & 0x7fffffffu) : ~u;
    float mx = __uint_as_float(b);
    int c = idx >> 5;
    int a = idx & 31;
    out[idx] = lines[(size_t)a * PDIM + c] / mx;
}

// ---------------------------------------------------------------- launch
extern "C" void kernel_launch(void* const* d_in, const int* in_sizes, int n_in,
                              void* d_out, int out_size, void* d_ws, size_t ws_size,
                              hipStream_t stream) {
    (void)in_sizes; (void)n_in; (void)out_size; (void)ws_size;
    const float* img = (const float*)d_in[0];
    float* out = (float*)d_out;

    __hip_bfloat16* Cbf   = (__hip_bfloat16*)d_ws;      // 8 MB
    __hip_bfloat16* imgbf = Cbf + 4194304;              // 8 MB
    __hip_bfloat16* uT    = imgbf + 4194304;            // 8 MB
    float* padded  = (float*)(uT + 4194304);            // 19.3 MB
    float* lines   = padded + (size_t)PDIM * PDIM;
    unsigned int* gmax = (unsigned int*)(lines + NLINE);

    hipMemsetAsync(padded, 0, (size_t)PDIM * PDIM * sizeof(float), stream);
    hipMemsetAsync(gmax, 0, sizeof(unsigned int), stream);

    gen_dct<<<16384, 256, 0, stream>>>(Cbf);
    cvt_img<<<4096, 256, 0, stream>>>(img, imgbf);

    dim3 gg(16, 16);
    gemm_bt<0><<<gg, 256, 0, stream>>>(imgbf, Cbf, uT, 2048, 0);      // uT = (img*C^T)^T
    gemm_bt<1><<<gg, 256, 0, stream>>>(uT, Cbf, padded, PDIM, PADB);  // padded = d

    AngleArgs aa;
    for (int i = 0; i < NANG; ++i) {
        float th = (float)((double)i * 3.14159265358979323846 / 31.0);
        float ca = (float)cos((double)th);
        float sa = (float)sin((double)th);
        aa.ca[i] = ca;
        aa.sa[i] = sa;
        aa.ox[i] = -1099.0f * (ca + sa - 1.0f);
        aa.oy[i] = -1099.0f * (ca - sa - 1.0f);
    }
    radon5<<<dim3(NWIN, NANG), 256, 0, stream>>>(padded, lines, aa);
    max_k<<<(NLINE + 255) / 256, 256, 0, stream>>>(lines, gmax);
    norm_k<<<(NLINE + 255) / 256, 256, 0, stream>>>(lines, gmax, out);
}

// Round 8
// 318.840 us; speedup vs baseline: 4.5333x; 1.1065x over previous
//
#include <hip/hip_runtime.h>
#include <hip/hip_bf16.h>
#include <math.h>

#define PDIM 2198
#define PDIM2 2252          // PDIM + 54-col zero halo (wrap-free staging in x)
#define PADB 75
#define NANG 32
#define NLINE (NANG * PDIM) // 70336

// radon geometry
#define CB 32      // c-values per block
#define RW 32      // r-values per window
#define NWIN 69    // ceil(2198/32)
#define TS 48      // staged box rows (span proof: <=47 used)
#define TSTRIDE 52 // staged cols per row; multiple of 4 for 16B staging
#define NBUF 4     // LDS buffers (stage 2 ahead needs 4 for race-freedom)

typedef __attribute__((ext_vector_type(8))) short bf16x8;
typedef __attribute__((ext_vector_type(4))) float f32x4;

#define GLOAD_LDS16(g, l)                                              \
    __builtin_amdgcn_global_load_lds(                                  \
        (const __attribute__((address_space(1))) void*)(g),            \
        (__attribute__((address_space(3))) void*)(l), 16, 0, 0)

#if __has_builtin(__builtin_amdgcn_fractf)
#define FRACTF(x) __builtin_amdgcn_fractf(x)
#else
#define FRACTF(x) ((x) - floorf(x))
#endif

// ---------------------------------------------------------------- DCT matrix (bf16)
__global__ void gen_dct(__hip_bfloat16* __restrict__ C) {
    int idx = blockIdx.x * 256 + threadIdx.x;
    int k = idx >> 11;
    int n = idx & 2047;
    int t = ((2 * n + 1) * k) & 8191;
    float s = sqrtf(((k == 0) ? 1.0f : 2.0f) / 2048.0f);
    C[idx] = __float2bfloat16(s * cospif((float)t * (1.0f / 4096.0f)));
}

// ---------------------------------------------------------------- img fp32 -> bf16
__global__ void cvt_img(const float* __restrict__ in, __hip_bfloat16* __restrict__ out) {
    int i = (blockIdx.x * 256 + threadIdx.x) * 4;
    float4 v = *(const float4*)(in + i);
    out[i + 0] = __float2bfloat16(v.x);
    out[i + 1] = __float2bfloat16(v.y);
    out[i + 2] = __float2bfloat16(v.z);
    out[i + 3] = __float2bfloat16(v.w);
}

// ---------------------------------------------------------------- MFMA GEMM (B^T form)
// D[row][col] = sum_k A[row][k]*B[col][k]; output stored TRANSPOSED out[col][row].
// 128x64 tile (BMxBN), BK=32, 256 thr = 4 waves (2Mx2N); wave = 64x32 out.
// grid: (N/64, M/128) = (32, 16) = 512 blocks -> 2 blocks/CU at N=2048.
template<int F32OUT>
__global__ __launch_bounds__(256) void gemm_bt(const __hip_bfloat16* __restrict__ A,
                                               const __hip_bfloat16* __restrict__ B,
                                               void* __restrict__ out,
                                               int ldo, int off) {
    __shared__ __hip_bfloat16 Al[128 * 32];
    __shared__ __hip_bfloat16 Bl[64 * 32];
    const int tid = threadIdx.x;
    const int wid = tid >> 6;
    const int lane = tid & 63;
    const int wr = wid >> 1, wc = wid & 1;
    const int l15 = lane & 15, lhi = lane >> 4;
    const int row0 = blockIdx.y * 128;
    const int col0 = blockIdx.x * 64;

    const __hip_bfloat16* gA = A + (size_t)(row0 + wid * 32 + (lane >> 2)) * 2048 + (lane & 3) * 8;
    const __hip_bfloat16* gB = B + (size_t)(col0 + wid * 16 + (lane >> 2)) * 2048 + (lane & 3) * 8;
    __hip_bfloat16* lA = Al + wid * 1024;   // 32 rows * 32
    __hip_bfloat16* lB = Bl + wid * 512;    // 16 rows * 32

    f32x4 acc[4][2] = {};

    for (int k0 = 0; k0 < 2048; k0 += 32) {
        GLOAD_LDS16(gA + k0, lA);
        GLOAD_LDS16(gA + 16 * 2048 + k0, lA + 16 * 32);
        GLOAD_LDS16(gB + k0, lB);
        __syncthreads();
        bf16x8 af[4], bfr[2];
#pragma unroll
        for (int m = 0; m < 4; ++m)
            af[m] = *(const bf16x8*)(Al + (wr * 64 + m * 16 + l15) * 32 + lhi * 8);
#pragma unroll
        for (int n = 0; n < 2; ++n)
            bfr[n] = *(const bf16x8*)(Bl + (wc * 32 + n * 16 + l15) * 32 + lhi * 8);
#pragma unroll
        for (int m = 0; m < 4; ++m)
#pragma unroll
            for (int n = 0; n < 2; ++n)
                acc[m][n] = __builtin_amdgcn_mfma_f32_16x16x32_bf16(af[m], bfr[n],
                                                                    acc[m][n], 0, 0, 0);
        __syncthreads();
    }

#pragma unroll
    for (int m = 0; m < 4; ++m) {
        const int row = row0 + wr * 64 + m * 16 + lhi * 4;
#pragma unroll
        for (int n = 0; n < 2; ++n) {
            const int col = col0 + wc * 32 + n * 16 + l15;
            f32x4 v = acc[m][n];
            if (F32OUT) {
                float* p = (float*)out + (size_t)(col + off) * ldo + off + row;
                p[0] = v[0]; p[1] = v[1]; p[2] = v[2]; p[3] = v[3];
            } else {
                __hip_bfloat16* p = (__hip_bfloat16*)out + (size_t)col * 2048 + row;
                p[0] = __float2bfloat16(v[0]);
                p[1] = __float2bfloat16(v[1]);
                p[2] = __float2bfloat16(v[2]);
                p[3] = __float2bfloat16(v[3]);
            }
        }
    }
}

// ---------------------------------------------------------------- radon
struct AngleArgs {
    float ca[NANG], sa[NANG], ox[NANG], oy[NANG];
};

// grid: (69 c-blocks, 32 angles), 256 threads = 4 waves, 8x8 (c,r) lane tile.
// 4-buffer pipeline, stage 2 windows ahead, counted vmcnt + raw s_barrier:
// loads stay in flight across barriers (T3/T4), no per-window vmcnt(0) drain.
__global__ __launch_bounds__(256) void radon6(const float* __restrict__ padded,
                                              float* __restrict__ lines,
                                              AngleArgs args) {
    __shared__ float tile[NBUF][TS * TSTRIDE];
    __shared__ float red[4][8];
    const int a = blockIdx.y;
    const int c0 = blockIdx.x * CB;
    const int t = threadIdx.x;
    const int wid = t >> 6, lane = t & 63;
    const int cl = lane >> 3;
    const int rl = lane & 7;
    const int c = c0 + wid * 8 + cl;
    const float ca = args.ca[a], sa = args.sa[a];   // sa >= 0 for theta in [0,pi]
    const float ox = args.ox[a], oy = args.oy[a];

    const float cf = (float)c;
    const float xbase = fmaf(ca, cf, ox);    // + sa*r
    const float ybase = fmaf(-sa, cf, oy);   // + ca*r

    const float xbMin = fminf(fmaf(ca, (float)c0, ox), fmaf(ca, (float)(c0 + CB - 1), ox));
    const float ybMin = fminf(fmaf(-sa, (float)c0, oy), fmaf(-sa, (float)(c0 + CB - 1), oy));
    const bool caPos = (ca >= 0.0f);

    float sum = 0.0f;

    auto origin = [&](int w, int& bx0, int& by0) {
        const float rx = (float)(w * RW);
        const float ry = caPos ? rx : (float)(w * RW + RW - 1);
        bx0 = (int)floorf(fmaf(sa, rx, xbMin)) - 1;
        by0 = (int)floorf(fmaf(ca, ry, ybMin)) - 1;
    };

    // always-fast staging: x-halo makes [bxs, bxs+51] wrap-free; 3 DMAs/wave.
    auto stage = [&](int buf, int bx0, int by0) {
        int bxs = bx0;                       // bx0 in [-457, 2652]
        bxs += (bxs < 0) ? PDIM : 0;
        bxs -= (bxs >= PDIM) ? PDIM : 0;     // [0, 2197]; +51 <= 2248 < PDIM2
        const int slab = wid * 12;           // 12 rows of 52 dwords per wave
#pragma unroll
        for (int iss = 0; iss < 3; ++iss) {
            const int d = iss * 256 + lane * 4;
            if (d < 12 * TSTRIDE) {
                const int rr = d / TSTRIDE;
                const int col = d - rr * TSTRIDE;
                int gy = by0 + slab + rr;
                gy += (gy < 0) ? PDIM : 0;
                gy -= (gy >= PDIM) ? PDIM : 0;
                GLOAD_LDS16(padded + (size_t)gy * PDIM2 + bxs + col,
                            &tile[buf][slab * TSTRIDE + iss * 256]);
            }
        }
    };

    auto compute = [&](int r0, int buf, int bx0, int by0, bool last) {
        // per-window bases: exact f32 sub (both multiples of 2^-12, <=24 bits)
        const float xbb = xbase - (float)bx0;
        const float ybb = ybase - (float)by0;
        const float* tb = &tile[buf][0];
#pragma unroll
        for (int k = 0; k < 4; ++k) {
            const int r = r0 + rl + 8 * k;
            const float rf = (float)r;
            const float xl = fmaf(sa, rf, xbb);
            const float yl = fmaf(ca, rf, ybb);
            const int xi = (int)xl;
            const int yi = (int)yl;
            const float wx = FRACTF(xl);
            const float wy = FRACTF(yl);
            const float* p = tb + yi * TSTRIDE + xi;
            const float v00 = p[0], v01 = p[1];
            const float v10 = p[TSTRIDE], v11 = p[TSTRIDE + 1];
            const float top = fmaf(wx, v01 - v00, v00);
            const float bot = fmaf(wx, v11 - v10, v10);
            if (!last || r < PDIM) sum = fmaf(wy, bot - top, sum + top);
        }
    };

    int bx[NWIN > 0 ? 4 : 4], by[4];   // ring of origins for w, w+1, w+2
    origin(0, bx[0], by[0]);
    stage(0, bx[0], by[0]);
    origin(1, bx[1], by[1]);
    stage(1, bx[1], by[1]);
    for (int w = 0; w < NWIN; ++w) {
        if (w + 2 < NWIN) {
            int bxn, byn;
            origin(w + 2, bxn, byn);
            bx[(w + 2) & 3] = bxn; by[(w + 2) & 3] = byn;
            stage((w + 2) & 3, bxn, byn);
        }
        // wait for stage(w) only; stage(w+1), stage(w+2) stay in flight.
        if (w < NWIN - 2)       asm volatile("s_waitcnt vmcnt(6)" ::: "memory");
        else if (w == NWIN - 2) asm volatile("s_waitcnt vmcnt(3)" ::: "memory");
        else                    asm volatile("s_waitcnt vmcnt(0)" ::: "memory");
        __builtin_amdgcn_s_barrier();
        __builtin_amdgcn_sched_barrier(0);   // rule #18: no ds_read hoist
        compute(w * RW, w & 3, bx[w & 3], by[w & 3], w == NWIN - 1);
    }

    sum += __shfl_xor(sum, 1, 64);
    sum += __shfl_xor(sum, 2, 64);
    sum += __shfl_xor(sum, 4, 64);
    if (rl == 0) red[wid][cl] = sum;
    __syncthreads();
    if (t < 32 && c0 + t < PDIM)
        lines[a * PDIM + c0 + t] = red[t >> 3][t & 7];
}

// ---------------------------------------------------------------- max
__global__ __launch_bounds__(256) void max_k(const float* __restrict__ lines,
                                             unsigned int* __restrict__ gmax) {
    const int idx = blockIdx.x * 256 + threadIdx.x;
    float m = (idx < NLINE) ? lines[idx] : -3.4e38f;
#pragma unroll
    for (int off = 32; off > 0; off >>= 1)
        m = fmaxf(m, __shfl_down(m, off, 64));
    __shared__ float wm[4];
    const int lane = threadIdx.x & 63, wid = threadIdx.x >> 6;
    if (lane == 0) wm[wid] = m;
    __syncthreads();
    if (threadIdx.x == 0) {
        float bm = fmaxf(fmaxf(wm[0], wm[1]), fmaxf(wm[2], wm[3]));
        unsigned int b = __float_as_uint(bm);
        unsigned int key = (b & 0x80000000u) ? ~b : (b | 0x80000000u);
        atomicMax(gmax, key);
    }
}

// ---------------------------------------------------------------- normalize
__global__ void norm_k(const float* __restrict__ lines,
                       const unsigned int* __restrict__ gmax,
                       float* __restrict__ out) {
    int idx = blockIdx.x * 256 + threadIdx.x;
    if (idx >= NLINE) return;
    unsigned int u = *gmax;
    unsigned int b = (u & 0x80000000u) ? (u & 0x7fffffffu) : ~u;
    float mx = __uint_as_float(b);
    int c = idx >> 5;
    int a = idx & 31;
    out[idx] = lines[(size_t)a * PDIM + c] / mx;
}

// ---------------------------------------------------------------- launch
extern "C" void kernel_launch(void* const* d_in, const int* in_sizes, int n_in,
                              void* d_out, int out_size, void* d_ws, size_t ws_size,
                              hipStream_t stream) {
    (void)in_sizes; (void)n_in; (void)out_size; (void)ws_size;
    const float* img = (const float*)d_in[0];
    float* out = (float*)d_out;

    __hip_bfloat16* Cbf   = (__hip_bfloat16*)d_ws;      // 8 MB
    __hip_bfloat16* imgbf = Cbf + 4194304;              // 8 MB
    __hip_bfloat16* uT    = imgbf + 4194304;            // 8 MB
    float* padded  = (float*)(uT + 4194304);            // 2198*2252*4 = 19.8 MB
    float* lines   = padded + (size_t)PDIM * PDIM2;
    unsigned int* gmax = (unsigned int*)(lines + NLINE);

    // zero image incl. halo cols [2198,2252) (they mirror zero-pad cols 0..53)
    hipMemsetAsync(padded, 0, (size_t)PDIM * PDIM2 * sizeof(float), stream);
    hipMemsetAsync(gmax, 0, sizeof(unsigned int), stream);

    gen_dct<<<16384, 256, 0, stream>>>(Cbf);
    cvt_img<<<4096, 256, 0, stream>>>(img, imgbf);

    gemm_bt<0><<<dim3(32, 16), 256, 0, stream>>>(imgbf, Cbf, uT, 2048, 0);
    gemm_bt<1><<<dim3(32, 16), 256, 0, stream>>>(uT, Cbf, padded, PDIM2, PADB);

    AngleArgs aa;
    for (int i = 0; i < NANG; ++i) {
        float th = (float)((double)i * 3.14159265358979323846 / 31.0);
        float ca = (float)cos((double)th);
        float sa = (float)sin((double)th);
        aa.ca[i] = ca;
        aa.sa[i] = sa;
        aa.ox[i] = -1099.0f * (ca + sa - 1.0f);
        aa.oy[i] = -1099.0f * (ca - sa - 1.0f);
    }
    radon6<<<dim3(NWIN, NANG), 256, 0, stream>>>(padded, lines, aa);
    max_k<<<(NLINE + 255) / 256, 256, 0, stream>>>(lines, gmax);
    norm_k<<<(NLINE + 255) / 256, 256, 0, stream>>>(lines, gmax, out);
}

// Round 10
// 304.603 us; speedup vs baseline: 4.7452x; 1.0467x over previous
//
#include <hip/hip_runtime.h>
#include <hip/hip_bf16.h>
#include <math.h>

#define PDIM 2198
#define PDIM2 2252          // PDIM + 54-col zero halo (wrap-free staging in x)
#define PADB 75
#define NANG 32
#define NLINE (NANG * PDIM) // 70336

// radon geometry
#define CB 32      // c-values per block
#define RW 32      // r-values per window
#define NWIN 69    // ceil(2198/32)
#define TS 48      // staged box rows (span proof: <=47 used)
#define TSTRIDE 52 // staged cols per row; multiple of 4 for 16B staging
#define NBUF 3     // ring; stage(w+2) issued AFTER barrier -> mod-3 safe

typedef __attribute__((ext_vector_type(8))) short bf16x8;
typedef __attribute__((ext_vector_type(4))) float f32x4;

template<bool L> struct BoolC { static constexpr bool value = L; };

#define GLOAD_LDS16(g, l)                                              \
    __builtin_amdgcn_global_load_lds(                                  \
        (const __attribute__((address_space(1))) void*)(g),            \
        (__attribute__((address_space(3))) void*)(l), 16, 0, 0)

#if __has_builtin(__builtin_amdgcn_fractf)
#define FRACTF(x) __builtin_amdgcn_fractf(x)
#else
#define FRACTF(x) ((x) - floorf(x))
#endif

// ---------------------------------------------------------------- DCT matrix (bf16)
__global__ void gen_dct(__hip_bfloat16* __restrict__ C) {
    int idx = blockIdx.x * 256 + threadIdx.x;
    int k = idx >> 11;
    int n = idx & 2047;
    int t = ((2 * n + 1) * k) & 8191;
    float s = sqrtf(((k == 0) ? 1.0f : 2.0f) / 2048.0f);
    C[idx] = __float2bfloat16(s * cospif((float)t * (1.0f / 4096.0f)));
}

// ---------------------------------------------------------------- img fp32 -> bf16
__global__ void cvt_img(const float* __restrict__ in, __hip_bfloat16* __restrict__ out) {
    int i = (blockIdx.x * 256 + threadIdx.x) * 4;
    float4 v = *(const float4*)(in + i);
    out[i + 0] = __float2bfloat16(v.x);
    out[i + 1] = __float2bfloat16(v.y);
    out[i + 2] = __float2bfloat16(v.z);
    out[i + 3] = __float2bfloat16(v.w);
}

// ---------------------------------------------------------------- zero pad borders
// Writes ONLY the elements gemm_bt<1> doesn't: rows [0,75)+[2123,2198) full
// width, middle rows' cols [0,75)+[2123,2252). 755592 elements (~3 MB).
__global__ __launch_bounds__(256) void pad_zero(float* __restrict__ padded) {
    int idx = blockIdx.x * 256 + threadIdx.x;
    const int TOPBOT = 2 * PADB * PDIM2;            // 337800
    if (idx < TOPBOT) {
        int r = idx / PDIM2;
        int c = idx - r * PDIM2;
        int row = (r < PADB) ? r : (2048 + r);      // 0..74 / 2123..2197
        padded[(size_t)row * PDIM2 + c] = 0.0f;
    } else {
        int i2 = idx - TOPBOT;
        if (i2 >= 2048 * 204) return;
        int rr = i2 / 204;
        int s = i2 - rr * 204;
        int col = (s < PADB) ? s : (2048 + s);      // 0..74 / 2123..2251
        padded[(size_t)(PADB + rr) * PDIM2 + col] = 0.0f;
    }
}

// ---------------------------------------------------------------- MFMA GEMM (B^T form)
// D[row][col] = sum_k A[row][k]*B[col][k]; output stored TRANSPOSED out[col][row].
// 128x64 tile, BK=32, 256 thr = 4 waves; grid (32,16)=512 blocks = 2/CU.
template<int F32OUT>
__global__ __launch_bounds__(256) void gemm_bt(const __hip_bfloat16* __restrict__ A,
                                               const __hip_bfloat16* __restrict__ B,
                                               void* __restrict__ out,
                                               int ldo, int off) {
    __shared__ __hip_bfloat16 Al[128 * 32];
    __shared__ __hip_bfloat16 Bl[64 * 32];
    const int tid = threadIdx.x;
    const int wid = tid >> 6;
    const int lane = tid & 63;
    const int wr = wid >> 1, wc = wid & 1;
    const int l15 = lane & 15, lhi = lane >> 4;
    const int row0 = blockIdx.y * 128;
    const int col0 = blockIdx.x * 64;

    const __hip_bfloat16* gA = A + (size_t)(row0 + wid * 32 + (lane >> 2)) * 2048 + (lane & 3) * 8;
    const __hip_bfloat16* gB = B + (size_t)(col0 + wid * 16 + (lane >> 2)) * 2048 + (lane & 3) * 8;
    __hip_bfloat16* lA = Al + wid * 1024;
    __hip_bfloat16* lB = Bl + wid * 512;

    f32x4 acc[4][2] = {};

    for (int k0 = 0; k0 < 2048; k0 += 32) {
        GLOAD_LDS16(gA + k0, lA);
        GLOAD_LDS16(gA + 16 * 2048 + k0, lA + 16 * 32);
        GLOAD_LDS16(gB + k0, lB);
        __syncthreads();
        bf16x8 af[4], bfr[2];
#pragma unroll
        for (int m = 0; m < 4; ++m)
            af[m] = *(const bf16x8*)(Al + (wr * 64 + m * 16 + l15) * 32 + lhi * 8);
#pragma unroll
        for (int n = 0; n < 2; ++n)
            bfr[n] = *(const bf16x8*)(Bl + (wc * 32 + n * 16 + l15) * 32 + lhi * 8);
#pragma unroll
        for (int m = 0; m < 4; ++m)
#pragma unroll
            for (int n = 0; n < 2; ++n)
                acc[m][n] = __builtin_amdgcn_mfma_f32_16x16x32_bf16(af[m], bfr[n],
                                                                    acc[m][n], 0, 0, 0);
        __syncthreads();
    }

#pragma unroll
    for (int m = 0; m < 4; ++m) {
        const int row = row0 + wr * 64 + m * 16 + lhi * 4;
#pragma unroll
        for (int n = 0; n < 2; ++n) {
            const int col = col0 + wc * 32 + n * 16 + l15;
            f32x4 v = acc[m][n];
            if (F32OUT) {
                float* p = (float*)out + (size_t)(col + off) * ldo + off + row;
                p[0] = v[0]; p[1] = v[1]; p[2] = v[2]; p[3] = v[3];
            } else {
                __hip_bfloat16* p = (__hip_bfloat16*)out + (size_t)col * 2048 + row;
                p[0] = __float2bfloat16(v[0]);
                p[1] = __float2bfloat16(v[1]);
                p[2] = __float2bfloat16(v[2]);
                p[3] = __float2bfloat16(v[3]);
            }
        }
    }
}

// ---------------------------------------------------------------- radon
struct AngleArgs {
    float ca[NANG], sa[NANG], ox[NANG], oy[NANG];
};

// grid: (69 c-blocks, 32 angles), 256 threads = 4 waves, 8x8 (c,r) lane tile.
// 3-buffer ring, stage 2 windows ahead issued AFTER the barrier (so the
// barrier orders stage(w+2) after compute(w-1), which shares buf (w+2)%3).
// Counted vmcnt: only stage(w) is awaited; stage(w+1) stays in flight.
__global__ __launch_bounds__(256) void radon7(const float* __restrict__ padded,
                                              float* __restrict__ lines,
                                              AngleArgs args) {
    __shared__ float tile[NBUF][TS * TSTRIDE];
    __shared__ float red[4][8];
    const int a = blockIdx.y;
    const int c0 = blockIdx.x * CB;
    const int t = threadIdx.x;
    const int wid = t >> 6, lane = t & 63;
    const int cl = lane >> 3;
    const int rl = lane & 7;
    const int c = c0 + wid * 8 + cl;
    const float ca = args.ca[a], sa = args.sa[a];   // sa >= 0 for theta in [0,pi]
    const float ox = args.ox[a], oy = args.oy[a];

    const float cf = (float)c;
    const float xbase = fmaf(ca, cf, ox);    // + sa*r
    const float ybase = fmaf(-sa, cf, oy);   // + ca*r

    const float xbMin = fminf(fmaf(ca, (float)c0, ox), fmaf(ca, (float)(c0 + CB - 1), ox));
    const float ybMin = fminf(fmaf(-sa, (float)c0, oy), fmaf(-sa, (float)(c0 + CB - 1), oy));
    const bool caPos = (ca >= 0.0f);

    float sum = 0.0f;

    auto origin = [&](int w, int& bx0, int& by0) {
        const float rx = (float)(w * RW);
        const float ry = caPos ? rx : (float)(w * RW + RW - 1);
        bx0 = (int)floorf(fmaf(sa, rx, xbMin)) - 1;
        by0 = (int)floorf(fmaf(ca, ry, ybMin)) - 1;
    };

    auto stage = [&](int buf, int bx0, int by0) {
        int bxs = bx0;
        bxs += (bxs < 0) ? PDIM : 0;
        bxs -= (bxs >= PDIM) ? PDIM : 0;     // [0,2197]; +51 <= 2248 < PDIM2
        const int slab = wid * 12;
#pragma unroll
        for (int iss = 0; iss < 3; ++iss) {
            const int d = iss * 256 + lane * 4;
            if (d < 12 * TSTRIDE) {
                const int rr = d / TSTRIDE;
                const int col = d - rr * TSTRIDE;
                int gy = by0 + slab + rr;
                gy += (gy < 0) ? PDIM : 0;
                gy -= (gy >= PDIM) ? PDIM : 0;
                GLOAD_LDS16(padded + (size_t)gy * PDIM2 + bxs + col,
                            &tile[buf][slab * TSTRIDE + iss * 256]);
            }
        }
    };

    auto computeT = [&](int r0, int buf, int bx0, int by0, auto lastc) {
        const float xbb = xbase - (float)bx0;   // exact f32 sub
        const float ybb = ybase - (float)by0;
        const float* tb = &tile[buf][0];
#pragma unroll
        for (int k = 0; k < 4; ++k) {
            const int r = r0 + rl + 8 * k;
            const float rf = (float)r;
            const float xl = fmaf(sa, rf, xbb);
            const float yl = fmaf(ca, rf, ybb);
            const int xi = (int)xl;
            const int yi = (int)yl;
            const float wx = FRACTF(xl);
            const float wy = FRACTF(yl);
            const float* p = tb + yi * TSTRIDE + xi;
            const float v00 = p[0], v01 = p[1];
            const float v10 = p[TSTRIDE], v11 = p[TSTRIDE + 1];
            const float top = fmaf(wx, v01 - v00, v00);
            const float bot = fmaf(wx, v11 - v10, v10);
            if (!decltype(lastc)::value || r < PDIM) sum = fmaf(wy, bot - top, sum + top);
        }
    };

    int bxr[3], byr[3];
    origin(0, bxr[0], byr[0]);
    stage(0, bxr[0], byr[0]);
    origin(1, bxr[1], byr[1]);
    stage(1, bxr[1], byr[1]);
    for (int w = 0; w < NWIN; ++w) {
        // outstanding here: stage(w) [maybe], stage(w+1) [if exists]
        if (w < NWIN - 1) asm volatile("s_waitcnt vmcnt(3)" ::: "memory");
        else              asm volatile("s_waitcnt vmcnt(0)" ::: "memory");
        __builtin_amdgcn_s_barrier();           // also orders compute(w-1) before stage(w+2)
        __builtin_amdgcn_sched_barrier(0);
        if (w + 2 < NWIN) {
            const int wn = (w + 2) % 3;
            origin(w + 2, bxr[wn], byr[wn]);
            stage(wn, bxr[wn], byr[wn]);        // latency hides under compute(w), compute(w+1)
        }
        const int wi = w % 3;
        if (w < NWIN - 1) computeT(w * RW, wi, bxr[wi], byr[wi], BoolC<false>{});
        else              computeT(w * RW, wi, bxr[wi], byr[wi], BoolC<true>{});
    }

    sum += __shfl_xor(sum, 1, 64);
    sum += __shfl_xor(sum, 2, 64);
    sum += __shfl_xor(sum, 4, 64);
    if (rl == 0) red[wid][cl] = sum;
    __syncthreads();
    if (t < 32 && c0 + t < PDIM)
        lines[a * PDIM + c0 + t] = red[t >> 3][t & 7];
}

// ---------------------------------------------------------------- max
__global__ __launch_bounds__(256) void max_k(const float* __restrict__ lines,
                                             unsigned int* __restrict__ gmax) {
    const int idx = blockIdx.x * 256 + threadIdx.x;
    float m = (idx < NLINE) ? lines[idx] : -3.4e38f;
#pragma unroll
    for (int off = 32; off > 0; off >>= 1)
        m = fmaxf(m, __shfl_down(m, off, 64));
    __shared__ float wm[4];
    const int lane = threadIdx.x & 63, wid = threadIdx.x >> 6;
    if (lane == 0) wm[wid] = m;
    __syncthreads();
    if (threadIdx.x == 0) {
        float bm = fmaxf(fmaxf(wm[0], wm[1]), fmaxf(wm[2], wm[3]));
        unsigned int b = __float_as_uint(bm);
        unsigned int key = (b & 0x80000000u) ? ~b : (b | 0x80000000u);
        atomicMax(gmax, key);
    }
}

// ---------------------------------------------------------------- normalize
__global__ void norm_k(const float* __restrict__ lines,
                       const unsigned int* __restrict__ gmax,
                       float* __restrict__ out) {
    int idx = blockIdx.x * 256 + threadIdx.x;
    if (idx >= NLINE) return;
    unsigned int u = *gmax;
    unsigned int b = (u & 0x80000000u) ? (u & 0x7fffffffu) : ~u;
    float mx = __uint_as_float(b);
    int c = idx >> 5;
    int a = idx & 31;
    out[idx] = lines[(size_t)a * PDIM + c] / mx;
}

// ---------------------------------------------------------------- launch
extern "C" void kernel_launch(void* const* d_in, const int* in_sizes, int n_in,
                              void* d_out, int out_size, void* d_ws, size_t ws_size,
                              hipStream_t stream) {
    (void)in_sizes; (void)n_in; (void)out_size; (void)ws_size;
    const float* img = (const float*)d_in[0];
    float* out = (float*)d_out;

    __hip_bfloat16* Cbf   = (__hip_bfloat16*)d_ws;      // 8 MB
    __hip_bfloat16* imgbf = Cbf + 4194304;              // 8 MB
    __hip_bfloat16* uT    = imgbf + 4194304;            // 8 MB
    float* padded  = (float*)(uT + 4194304);            // 2198*2252*4 = 19.8 MB
    float* lines   = padded + (size_t)PDIM * PDIM2;
    unsigned int* gmax = (unsigned int*)(lines + NLINE);

    (void)hipMemsetAsync(gmax, 0, sizeof(unsigned int), stream);

    gen_dct<<<16384, 256, 0, stream>>>(Cbf);
    cvt_img<<<4096, 256, 0, stream>>>(img, imgbf);
    pad_zero<<<(2 * PADB * PDIM2 + 2048 * 204 + 255) / 256, 256, 0, stream>>>(padded);

    gemm_bt<0><<<dim3(32, 16), 256, 0, stream>>>(imgbf, Cbf, uT, 2048, 0);
    gemm_bt<1><<<dim3(32, 16), 256, 0, stream>>>(uT, Cbf, padded, PDIM2, PADB);

    AngleArgs aa;
    for (int i = 0; i < NANG; ++i) {
        float th = (float)((double)i * 3.14159265358979323846 / 31.0);
        float ca = (float)cos((double)th);
        float sa = (float)sin((double)th);
        aa.ca[i] = ca;
        aa.sa[i] = sa;
        aa.ox[i] = -1099.0f * (ca + sa - 1.0f);
        aa.oy[i] = -1099.0f * (ca - sa - 1.0f);
    }
    radon7<<<dim3(NWIN, NANG), 256, 0, stream>>>(padded, lines, aa);
    max_k<<<(NLINE + 255) / 256, 256, 0, stream>>>(lines, gmax);
    norm_k<<<(NLINE + 255) / 256, 256, 0, stream>>>(lines, gmax, out);
}